// Round 8
// baseline (2755.673 us; speedup 1.0000x reference)
//
#include <hip/hip_runtime.h>
#include <math.h>

#define NB 4
#define NPTS 20000
#define NC 256
#define NV 300
#define NSAMP 1024

// d_out float offsets (outputs concatenated flat in reference return order)
#define O_GS    0         // graspness_score  [B,N]
#define O_INDS  80000     // graspable_inds   [B,NS] (as float)
#define O_XYZ   84096     // graspable_xyz    [B,NS,3]
#define O_FEAT  96384     // graspable_feats  [B,C,NS]
#define O_FP2   1144960   // fp2_graspness    [B,NS]
#define O_VS    1149056   // view_score       [B,NS,V]
#define O_TVI   2377856   // top_view_inds    [B,NS] (as float)
#define O_TVS   2381952   // top_view_scores  [B,NS]
#define O_VPX   2386048   // vp_xyz           [B,NS,3]
#define O_ROT   2398336   // vp_rot           [B,NS,3,3]

#define FPS_T 512
#define MAXPP 40     // ceil(NPTS / FPS_T)
#define LDSM  4096   // max compacted points kept in LDS

// ---------------------------------------------------------------------------
// Kernel A: fused graspable head as LDS-staged GEMM (bit-identical op order
// to the original per-point kernel). Launched once. Unchanged this round.
// ---------------------------------------------------------------------------
__global__ __launch_bounds__(256, 1) void graspness_kernel(
    const float* __restrict__ feat, const float* __restrict__ w1,
    const float* __restrict__ b1, const float* __restrict__ g1,
    const float* __restrict__ be1, const float* __restrict__ m1,
    const float* __restrict__ v1, const float* __restrict__ w2,
    const float* __restrict__ b2, float* __restrict__ out)
{
    __shared__ float Fs[NC][64];     // 64 KB: full K x 64 points
    __shared__ float Xs[NC][65];     // 66.6 KB: relu(bn(conv)) tile (+1 pad)
    __shared__ float As[2][16][64];  // 8 KB: W1 k-tile double buffer

    int b  = blockIdx.z;
    int n0 = blockIdx.x * 64;
    int tid = threadIdx.x;
    int tx = tid & 15, ty = tid >> 4;
    int rem = NPTS - n0; if (rem > 64) rem = 64;

    {
        int j  = tid & 63;
        int kb = tid >> 6;                       // 0..3
        const float* fb = feat + (size_t)b * NC * NPTS + n0;
        bool ok = (j < rem);
#pragma unroll
        for (int r = 0; r < 64; ++r) {
            int k = r * 4 + kb;
            Fs[k][j] = ok ? fb[(size_t)k * NPTS + j] : 0.f;
        }
    }

#pragma unroll
    for (int p = 0; p < 4; ++p) {
        int m_l = ty + p * 16;
        As[0][tx][m_l] = w1[(size_t)m_l * NC + tx];
    }
    __syncthreads();

    float acc[4][4][4];   // [i ch][j pt][c = k%4] -- statically indexed

    for (int s = 0; s < 64; ++s) {
        int ob = s >> 4, kt = s & 15;

        if (kt == 0) {
#pragma unroll
            for (int i = 0; i < 4; ++i)
#pragma unroll
                for (int j = 0; j < 4; ++j)
#pragma unroll
                    for (int c = 0; c < 4; ++c) acc[i][j][c] = 0.f;
        }

        if (s + 1 < 64) {
            int ob2 = (s + 1) >> 4, kt2 = (s + 1) & 15;
#pragma unroll
            for (int p = 0; p < 4; ++p) {
                int m_l = ty + p * 16;
                As[(s + 1) & 1][tx][m_l] =
                    w1[(size_t)(ob2 * 64 + m_l) * NC + kt2 * 16 + tx];
            }
        }

        const int buf = s & 1;
#pragma unroll
        for (int kk = 0; kk < 16; ++kk) {
            float4 a = *reinterpret_cast<const float4*>(&As[buf][kk][ty * 4]);
            float4 f = *reinterpret_cast<const float4*>(&Fs[kt * 16 + kk][tx * 4]);
            const int c = kk & 3;
            acc[0][0][c] += a.x * f.x; acc[0][1][c] += a.x * f.y;
            acc[0][2][c] += a.x * f.z; acc[0][3][c] += a.x * f.w;
            acc[1][0][c] += a.y * f.x; acc[1][1][c] += a.y * f.y;
            acc[1][2][c] += a.y * f.z; acc[1][3][c] += a.y * f.w;
            acc[2][0][c] += a.z * f.x; acc[2][1][c] += a.z * f.y;
            acc[2][2][c] += a.z * f.z; acc[2][3][c] += a.z * f.w;
            acc[3][0][c] += a.w * f.x; acc[3][1][c] += a.w * f.y;
            acc[3][2][c] += a.w * f.z; acc[3][3][c] += a.w * f.w;
        }

        if (kt == 15) {
#pragma unroll
            for (int i = 0; i < 4; ++i) {
                int o = ob * 64 + ty * 4 + i;
                float bo = b1[o];
                float sc = g1[o] / sqrtf(v1[o] + 1e-5f);
                float mo = m1[o], beo = be1[o];
#pragma unroll
                for (int j = 0; j < 4; ++j) {
                    float y = (acc[i][j][0] + acc[i][j][1]) +
                              (acc[i][j][2] + acc[i][j][3]) + bo;
                    float r = (y - mo) * sc + beo;
                    r = fmaxf(r, 0.f);
                    Xs[o][tx * 4 + j] = r;
                }
            }
        }
        __syncthreads();
    }

    if (tid < 64 && tid < rem) {
        float gs = 0.f;
#pragma unroll 8
        for (int o = 0; o < NC; ++o) {
            gs += w2[o] * Xs[o][tid];
        }
        out[(size_t)b * NPTS + n0 + tid] = gs + b2[0];
    }
}

// ---------------------------------------------------------------------------
// cross-lane helpers
// ---------------------------------------------------------------------------
template<int CTRL>
__device__ __forceinline__ unsigned long long dpp_u64(unsigned long long x)
{
    int lo = __builtin_amdgcn_update_dpp(0, (int)(unsigned)(x & 0xffffffffull),
                                         CTRL, 0xF, 0xF, false);
    int hi = __builtin_amdgcn_update_dpp(0, (int)(unsigned)(x >> 32),
                                         CTRL, 0xF, 0xF, false);
    return ((unsigned long long)(unsigned)hi << 32) | (unsigned)lo;
}

__device__ __forceinline__ unsigned long long swz16_u64(unsigned long long x)
{
    // ds_swizzle BitMode xor 16: offset = (16<<10) | 0x1F = 0x401F
    unsigned lo = (unsigned)__builtin_amdgcn_ds_swizzle((int)(unsigned)(x & 0xffffffffull), 0x401F);
    unsigned hi = (unsigned)__builtin_amdgcn_ds_swizzle((int)(unsigned)(x >> 32), 0x401F);
    return ((unsigned long long)hi << 32) | lo;
}

// ---------------------------------------------------------------------------
// Single-wave FPS core (M <= 3072): wave 0 runs the whole loop.
// No barriers, no LDS tree. Wave reduce = 6 DPP steps to lane 63
// (quad_perm xor1/xor2, row_ror4/8, row_bcast15/31) + one readlane.
// Distance arithmetic identical (__f*_rn chain) -> same trajectory.
// ---------------------------------------------------------------------------
template<int TIER>
__device__ __forceinline__ void fps_core_w0(
    int t, int M, int cnt2,
    const float* __restrict__ cxL, const float* __restrict__ cyL,
    const float* __restrict__ czL,
    int* __restrict__ hist)
{
    int mybase = t * cnt2;
    int mycount = M - mybase;
    if (mycount > cnt2) mycount = cnt2;
    if (mycount < 0) mycount = 0;

    float rx[TIER], ry[TIER], rz[TIER], dd[TIER];
#pragma unroll
    for (int j = 0; j < TIER; ++j) {
        if (j < mycount) {
            rx[j] = cxL[mybase + j];
            ry[j] = cyL[mybase + j];
            rz[j] = czL[mybase + j];
            dd[j] = 1e10f;
        }
    }

    float wx = cxL[0], wy = cyL[0], wz = czL[0];
    int winner = 0;

    for (int it = 0; it < NSAMP; ++it) {
        if (t == 0) hist[it] = winner;

        // per-lane best: strict >, ascending j keeps lowest pos on ties
        float bv = -2.f; int bc = 0x7fffffff;
#pragma unroll
        for (int j = 0; j < TIER; ++j) {
            if (j < mycount) {
                float dx = __fsub_rn(rx[j], wx);
                float dy = __fsub_rn(ry[j], wy);
                float dz = __fsub_rn(rz[j], wz);
                float d  = __fadd_rn(__fadd_rn(__fmul_rn(dx, dx), __fmul_rn(dy, dy)),
                                     __fmul_rn(dz, dz));
                float nd = fminf(dd[j], d);
                dd[j] = nd;
                if (nd > bv) { bv = nd; bc = mybase + j; }
            }
        }

        // packed key: value bits (>=0, unsigned-monotonic) | ~pos (min pos on ties)
        unsigned long long pk = (bc == 0x7fffffff)
            ? 0ull
            : (((unsigned long long)__float_as_uint(bv) << 32) | (unsigned)(~bc));

        // all-DPP max-reduce; result valid in lane 63.
        // (helper returns 0 for lanes with no source -> harmless under max)
        { unsigned long long o = dpp_u64<0xB1>(pk);  if (o > pk) pk = o; }  // quad xor1
        { unsigned long long o = dpp_u64<0x4E>(pk);  if (o > pk) pk = o; }  // quad xor2
        { unsigned long long o = dpp_u64<0x124>(pk); if (o > pk) pk = o; }  // row_ror:4
        { unsigned long long o = dpp_u64<0x128>(pk); if (o > pk) pk = o; }  // row_ror:8
        { unsigned long long o = dpp_u64<0x142>(pk); if (o > pk) pk = o; }  // row_bcast15
        { unsigned long long o = dpp_u64<0x143>(pk); if (o > pk) pk = o; }  // row_bcast31

        unsigned lo = (unsigned)__builtin_amdgcn_readlane((int)(unsigned)(pk & 0xffffffffull), 63);
        int pos = (int)(~lo);
        winner = pos;
        wx = cxL[pos]; wy = cyL[pos]; wz = czL[pos];   // one broadcast LDS hop
    }
}

// ---------------------------------------------------------------------------
// 8-wave FPS core (v2, measured 765us) — fallback for M > 3072.
// ---------------------------------------------------------------------------
template<int TIER, bool USE_LDS>
__device__ __forceinline__ void fps_core2(
    int t, int M, int cnt2,
    const float* __restrict__ cxg, const float* __restrict__ cyg,
    const float* __restrict__ czg,
    const float* __restrict__ cxL, const float* __restrict__ cyL,
    const float* __restrict__ czL,
    int* __restrict__ hist, unsigned long long (*pkL)[8])
{
    int mybase = t * cnt2;
    int mycount = M - mybase;
    if (mycount > cnt2) mycount = cnt2;
    if (mycount < 0) mycount = 0;

    float rx[TIER], ry[TIER], rz[TIER], dd[TIER];
#pragma unroll
    for (int j = 0; j < TIER; ++j) {
        if (j < mycount) {
            rx[j] = USE_LDS ? cxL[mybase + j] : cxg[mybase + j];
            ry[j] = USE_LDS ? cyL[mybase + j] : cyg[mybase + j];
            rz[j] = USE_LDS ? czL[mybase + j] : czg[mybase + j];
            dd[j] = 1e10f;
        }
    }

    float wx = USE_LDS ? cxL[0] : cxg[0];
    float wy = USE_LDS ? cyL[0] : cyg[0];
    float wz = USE_LDS ? czL[0] : czg[0];
    int winner = 0;
    int w = t >> 6;

    for (int it = 0; it < NSAMP; ++it) {
        if (t == 0) hist[it] = winner;

        float bv = -2.f; int bc = 0x7fffffff;
#pragma unroll
        for (int j = 0; j < TIER; ++j) {
            if (j < mycount) {
                float dx = __fsub_rn(rx[j], wx);
                float dy = __fsub_rn(ry[j], wy);
                float dz = __fsub_rn(rz[j], wz);
                float d  = __fadd_rn(__fadd_rn(__fmul_rn(dx, dx), __fmul_rn(dy, dy)),
                                     __fmul_rn(dz, dz));
                float nd = fminf(dd[j], d);
                dd[j] = nd;
                if (nd > bv) { bv = nd; bc = mybase + j; }
            }
        }

        unsigned long long pk = (bc == 0x7fffffff)
            ? 0ull
            : (((unsigned long long)__float_as_uint(bv) << 32) | (unsigned)(~bc));

        { unsigned long long o = dpp_u64<0xB1>(pk);  if (o > pk) pk = o; }
        { unsigned long long o = dpp_u64<0x4E>(pk);  if (o > pk) pk = o; }
        { unsigned long long o = dpp_u64<0x124>(pk); if (o > pk) pk = o; }
        { unsigned long long o = dpp_u64<0x128>(pk); if (o > pk) pk = o; }
        { unsigned long long o = swz16_u64(pk);      if (o > pk) pk = o; }
        { unsigned long long o = __shfl_xor(pk, 32, 64); if (o > pk) pk = o; }

        int par = it & 1;
        if ((t & 63) == 0) pkL[par][w] = pk;
        __syncthreads();

        unsigned long long a0 = pkL[par][0], a1 = pkL[par][1];
        unsigned long long a2 = pkL[par][2], a3 = pkL[par][3];
        unsigned long long a4 = pkL[par][4], a5 = pkL[par][5];
        unsigned long long a6 = pkL[par][6], a7 = pkL[par][7];
        if (a1 > a0) a0 = a1;
        if (a3 > a2) a2 = a3;
        if (a5 > a4) a4 = a5;
        if (a7 > a6) a6 = a7;
        if (a2 > a0) a0 = a2;
        if (a6 > a4) a4 = a6;
        if (a4 > a0) a0 = a4;

        int pos = (int)(~(unsigned)(a0 & 0xffffffffull));
        winner = pos;
        wx = USE_LDS ? cxL[pos] : cxg[pos];
        wy = USE_LDS ? cyL[pos] : cyg[pos];
        wz = USE_LDS ? czL[pos] : czg[pos];
    }
}

// ---------------------------------------------------------------------------
// Kernel B: per-batch masked FPS (one workgroup per batch).
// ---------------------------------------------------------------------------
__global__ __launch_bounds__(FPS_T, 2) void fps_kernel(
    const float* __restrict__ xyz, const float* __restrict__ gs,
    float* __restrict__ out_f, int* __restrict__ out_i,
    int* __restrict__ cidx, float* __restrict__ cx,
    float* __restrict__ cy, float* __restrict__ cz)
{
    int b = blockIdx.x;
    int t = threadIdx.x;
    __shared__ int sA[FPS_T], sB[FPS_T];
    __shared__ unsigned long long pkL[2][8];
    __shared__ int hist[NSAMP];
    __shared__ float cxL[LDSM], cyL[LDSM], czL[LDSM];
    __shared__ int cidxL[LDSM];

    const float* gsb = gs + (size_t)b * NPTS;
    const float* xb  = xyz + (size_t)b * NPTS * 3;

    // ---- phase 1: count valid in my contiguous chunk ----
    int base = t * MAXPP;
    unsigned long long vmask = 0ull;
    int cnt = 0;
#pragma unroll
    for (int j = 0; j < MAXPP; ++j) {
        int p = base + j;
        if (p < NPTS) {
            if (gsb[p] > 0.09f) { vmask |= (1ull << j); ++cnt; }
        }
    }
    sA[t] = cnt;
    __syncthreads();
    // Hillis-Steele inclusive scan (ping-pong)
    int* src = sA; int* dst = sB;
    for (int off = 1; off < FPS_T; off <<= 1) {
        int v = src[t];
        if (t >= off) v += src[t - off];
        dst[t] = v;
        __syncthreads();
        int* tmp = src; src = dst; dst = tmp;
    }
    int M = src[FPS_T - 1];
    int excl = src[t] - cnt;
    bool useLds = (M <= LDSM);

    // ---- ordered compacted write (preserves index order => argmax ties OK) ----
    {
        int pos = excl;
#pragma unroll
        for (int j = 0; j < MAXPP; ++j) {
            if (vmask & (1ull << j)) {
                int p = base + j;
                if (useLds) {
                    cidxL[pos] = p;
                    cxL[pos] = xb[p * 3 + 0];
                    cyL[pos] = xb[p * 3 + 1];
                    czL[pos] = xb[p * 3 + 2];
                } else {
                    int gp = b * NPTS + pos;
                    cidx[gp] = p;
                    cx[gp] = xb[p * 3 + 0];
                    cy[gp] = xb[p * 3 + 1];
                    cz[gp] = xb[p * 3 + 2];
                }
                ++pos;
            }
        }
    }
    __syncthreads();

    if (M > 0 && M <= 3072) {
        // single-wave path: wave 0 only; no further barriers in the block.
        if (t < 64) {
            int cw = (M + 63) >> 6;
            if (cw <= 16)      fps_core_w0<16>(t, M, cw, cxL, cyL, czL, hist);
            else if (cw <= 32) fps_core_w0<32>(t, M, cw, cxL, cyL, czL, hist);
            else               fps_core_w0<48>(t, M, cw, cxL, cyL, czL, hist);

            for (int s = t; s < NSAMP; s += 64) {
                int oi = cidxL[hist[s]];
                out_f[b * NSAMP + s] = (float)oi;
                out_i[b * NSAMP + s] = oi;
            }
        }
    } else if (M > 0) {
        const float* cxg = cx + b * NPTS;
        const float* cyg = cy + b * NPTS;
        const float* czg = cz + b * NPTS;

        if (useLds) {
            fps_core2<8, true>(t, M, (M + FPS_T - 1) / FPS_T, cxg, cyg, czg,
                               cxL, cyL, czL, hist, pkL);
        } else {
            int cnt2 = (M + FPS_T - 1) / FPS_T;
            if (cnt2 <= 16)      fps_core2<16, false>(t, M, cnt2, cxg, cyg, czg, cxL, cyL, czL, hist, pkL);
            else if (cnt2 <= 24) fps_core2<24, false>(t, M, cnt2, cxg, cyg, czg, cxL, cyL, czL, hist, pkL);
            else                 fps_core2<40, false>(t, M, cnt2, cxg, cyg, czg, cxL, cyL, czL, hist, pkL);
        }

        __syncthreads();
        for (int s = t; s < NSAMP; s += FPS_T) {
            int hp = hist[s];
            int oi = useLds ? cidxL[hp] : cidx[b * NPTS + hp];
            out_f[b * NSAMP + s] = (float)oi;
            out_i[b * NSAMP + s] = oi;
        }
    } else {
        for (int s = t; s < NSAMP; s += FPS_T) {
            out_f[b * NSAMP + s] = 0.f;
            out_i[b * NSAMP + s] = 0;
        }
    }
}

// ---------------------------------------------------------------------------
// gathers
// ---------------------------------------------------------------------------
__global__ void gather_xyz_kernel(const float* __restrict__ xyz,
                                  const int* __restrict__ inds,
                                  float* __restrict__ dout)
{
    int i = blockIdx.x * 256 + threadIdx.x;
    if (i >= NB * NSAMP) return;
    int b = i >> 10;
    int ind = inds[i];
    const float* p = xyz + ((size_t)b * NPTS + ind) * 3;
    dout[O_XYZ + (size_t)i * 3 + 0] = p[0];
    dout[O_XYZ + (size_t)i * 3 + 1] = p[1];
    dout[O_XYZ + (size_t)i * 3 + 2] = p[2];
    dout[O_FP2 + i] = dout[O_GS + (size_t)b * NPTS + ind];
}

__global__ void gather_feat_kernel(const float* __restrict__ feat,
                                   const int* __restrict__ inds,
                                   float* __restrict__ dout)
{
    int c = blockIdx.x, b = blockIdx.y, s = threadIdx.x;   // 1024 threads
    int ind = inds[b * NSAMP + s];
    dout[O_FEAT + ((size_t)b * NC + c) * NSAMP + s] =
        feat[((size_t)b * NC + c) * NPTS + ind];
}

// ---------------------------------------------------------------------------
// fp32 tiled GEMM: C[b] = A[M,K] x Bsrc[b][K,1024], 64x64 tile, 4x4 micro.
// EPI 0/1: +bias, BN, ReLU -> Cdst[b][c][n].  EPI 2: +bias -> d_out transposed.
// ---------------------------------------------------------------------------
template<int EPI>
__global__ __launch_bounds__(256) void gemm_epi_kernel(
    const float* __restrict__ A, const float* __restrict__ Bsrc,
    int M, int K, size_t bstride,
    const float* __restrict__ bias, const float* __restrict__ gg,
    const float* __restrict__ bb, const float* __restrict__ mm,
    const float* __restrict__ vv,
    float* __restrict__ Cdst, size_t cstride)
{
    __shared__ float As[16][68];
    __shared__ float Bs[16][68];
    int tid = threadIdx.x;
    int n0 = blockIdx.x * 64;
    int m0 = blockIdx.y * 64;
    int b  = blockIdx.z;
    const float* Bb = Bsrc + (size_t)b * bstride;
    int tx = tid & 15, ty = tid >> 4;
    float acc[4][4] = {};
    int nk = (K + 15) >> 4;
    for (int kt = 0; kt < nk; ++kt) {
        int k0 = kt * 16;
#pragma unroll
        for (int p = 0; p < 4; ++p) {   // A tile: 64 m x 16 k, transposed store
            int m_l = ty + p * 16;
            int gm = m0 + m_l, gk = k0 + tx;
            float va = (gm < M && gk < K) ? A[(size_t)gm * K + gk] : 0.f;
            As[tx][m_l] = va;
        }
#pragma unroll
        for (int p = 0; p < 4; ++p) {   // B tile: 16 k x 64 n
            int k_l = (tid >> 6) + p * 4;
            int n_l = tid & 63;
            int gk = k0 + k_l;
            float vb = (gk < K) ? Bb[(size_t)gk * NSAMP + n0 + n_l] : 0.f;
            Bs[k_l][n_l] = vb;
        }
        __syncthreads();
#pragma unroll
        for (int kk = 0; kk < 16; ++kk) {
            float a0 = As[kk][ty * 4 + 0], a1 = As[kk][ty * 4 + 1];
            float a2 = As[kk][ty * 4 + 2], a3 = As[kk][ty * 4 + 3];
            float c0 = Bs[kk][tx * 4 + 0], c1 = Bs[kk][tx * 4 + 1];
            float c2 = Bs[kk][tx * 4 + 2], c3 = Bs[kk][tx * 4 + 3];
            acc[0][0] += a0 * c0; acc[0][1] += a0 * c1; acc[0][2] += a0 * c2; acc[0][3] += a0 * c3;
            acc[1][0] += a1 * c0; acc[1][1] += a1 * c1; acc[1][2] += a1 * c2; acc[1][3] += a1 * c3;
            acc[2][0] += a2 * c0; acc[2][1] += a2 * c1; acc[2][2] += a2 * c2; acc[2][3] += a2 * c3;
            acc[3][0] += a3 * c0; acc[3][1] += a3 * c1; acc[3][2] += a3 * c2; acc[3][3] += a3 * c3;
        }
        __syncthreads();
    }
#pragma unroll
    for (int i = 0; i < 4; ++i) {
        int c = m0 + ty * 4 + i;
        if (c >= M) continue;
        float bi = bias[c];
        float scl = 0.f, sh = 0.f, mc = 0.f;
        if constexpr (EPI < 2) {
            scl = gg[c] / sqrtf(vv[c] + 1e-5f);
            sh = bb[c];
            mc = mm[c];
        }
#pragma unroll
        for (int j = 0; j < 4; ++j) {
            int n = n0 + tx * 4 + j;
            float v = acc[i][j] + bi;
            if constexpr (EPI < 2) {
                v = (v - mc) * scl + sh;
                v = fmaxf(v, 0.f);
                Cdst[(size_t)b * cstride + (size_t)c * NSAMP + n] = v;
            } else {
                Cdst[((size_t)b * NSAMP + n) * NV + c] = v;   // transposed [B,NS,V]
            }
        }
    }
}

// ---------------------------------------------------------------------------
// final: per-(b,s) argmax over 300 views, fibonacci-sphere view (f64 like numpy),
// rotation matrix (angle = 0  =>  R = [axis_x | axis_y | axis_z])
// ---------------------------------------------------------------------------
__global__ void view_kernel(float* __restrict__ dout)
{
    int i = blockIdx.x * 256 + threadIdx.x;
    if (i >= NB * NSAMP) return;
    const float* vs = dout + O_VS + (size_t)i * NV;
    float best = vs[0]; int bi = 0;
    for (int v = 1; v < NV; ++v) {
        float x = vs[v];
        if (x > best) { best = x; bi = v; }
    }
    dout[O_TVS + i] = best;
    dout[O_TVI + i] = (float)bi;

    const double PHI = (sqrt(5.0) - 1.0) / 2.0;
    double z = (2.0 * (double)bi + 1.0) / 300.0 - 1.0;
    double rr = sqrt(fmax(1.0 - z * z, 0.0));
    double ang = (2.0 * 3.14159265358979323846 * (double)bi) * PHI;
    float vx = (float)(rr * cos(ang));
    float vy = (float)(rr * sin(ang));
    float vz = (float)z;
    dout[O_VPX + (size_t)i * 3 + 0] = vx;
    dout[O_VPX + (size_t)i * 3 + 1] = vy;
    dout[O_VPX + (size_t)i * 3 + 2] = vz;

    float tx = -vx, ty = -vy, tz = -vz;
    float ayx = -ty, ayy = tx, ayz = 0.f;
    float ny = sqrtf(ayx * ayx + ayy * ayy + ayz * ayz);
    if (ny == 0.f) { ayx = 0.f; ayy = 1.f; ayz = 0.f; }
    float nx = sqrtf(tx * tx + ty * ty + tz * tz);
    float axx = tx / nx, axy = ty / nx, axz = tz / nx;
    float ny2 = sqrtf(ayx * ayx + ayy * ayy + ayz * ayz);
    ayx /= ny2; ayy /= ny2; ayz /= ny2;
    float azx = axy * ayz - axz * ayy;
    float azy = axz * ayx - axx * ayz;
    float azz = axx * ayy - axy * ayx;
    float* R = dout + O_ROT + (size_t)i * 9;
    R[0] = axx; R[1] = ayx; R[2] = azx;
    R[3] = axy; R[4] = ayy; R[5] = azy;
    R[6] = axz; R[7] = ayz; R[8] = azz;
}

// ---------------------------------------------------------------------------
extern "C" void kernel_launch(void* const* d_in, const int* in_sizes, int n_in,
                              void* d_out, int out_size, void* d_ws, size_t ws_size,
                              hipStream_t stream)
{
    const float* seed_xyz  = (const float*)d_in[0];
    const float* seed_feat = (const float*)d_in[1];
    const float* gh_w1 = (const float*)d_in[2];
    const float* gh_b1 = (const float*)d_in[3];
    const float* gh_g1 = (const float*)d_in[4];
    const float* gh_be1 = (const float*)d_in[5];
    const float* gh_m1 = (const float*)d_in[6];
    const float* gh_v1 = (const float*)d_in[7];
    const float* gh_w2 = (const float*)d_in[8];
    const float* gh_b2 = (const float*)d_in[9];
    const float* w1 = (const float*)d_in[10];
    const float* b1 = (const float*)d_in[11];
    const float* g1 = (const float*)d_in[12];
    const float* be1 = (const float*)d_in[13];
    const float* m1 = (const float*)d_in[14];
    const float* v1 = (const float*)d_in[15];
    const float* w2 = (const float*)d_in[16];
    const float* b2 = (const float*)d_in[17];
    const float* g2 = (const float*)d_in[18];
    const float* be2 = (const float*)d_in[19];
    const float* m2 = (const float*)d_in[20];
    const float* v2 = (const float*)d_in[21];
    const float* w3 = (const float*)d_in[22];
    const float* b3 = (const float*)d_in[23];

    float* out = (float*)d_out;

    // workspace layout (~10.4 MB)
    int*   ws_inds = (int*)d_ws;                     // B*NS
    int*   ws_cidx = ws_inds + NB * NSAMP;           // B*NPTS
    float* ws_cx = (float*)(ws_cidx + NB * NPTS);    // B*NPTS
    float* ws_cy = ws_cx + NB * NPTS;
    float* ws_cz = ws_cy + NB * NPTS;
    float* ws_g1 = ws_cz + NB * NPTS;                // B*256*1024
    float* ws_g2 = ws_g1 + (size_t)NB * NC * NSAMP;  // B*300*1024

    graspness_kernel<<<dim3(313, 1, NB), 256, 0, stream>>>(
        seed_feat, gh_w1, gh_b1, gh_g1, gh_be1, gh_m1, gh_v1, gh_w2, gh_b2,
        out + O_GS);

    fps_kernel<<<NB, FPS_T, 0, stream>>>(
        seed_xyz, out + O_GS, out + O_INDS, ws_inds,
        ws_cidx, ws_cx, ws_cy, ws_cz);

    gather_xyz_kernel<<<(NB * NSAMP + 255) / 256, 256, 0, stream>>>(
        seed_xyz, ws_inds, out);

    gather_feat_kernel<<<dim3(NC, NB), 1024, 0, stream>>>(
        seed_feat, ws_inds, out);

    gemm_epi_kernel<0><<<dim3(16, 4, NB), 256, 0, stream>>>(
        w1, out + O_FEAT, NC, NC, (size_t)NC * NSAMP,
        b1, g1, be1, m1, v1, ws_g1, (size_t)NC * NSAMP);

    gemm_epi_kernel<1><<<dim3(16, 5, NB), 256, 0, stream>>>(
        w2, ws_g1, NV, NC, (size_t)NC * NSAMP,
        b2, g2, be2, m2, v2, ws_g2, (size_t)NV * NSAMP);

    gemm_epi_kernel<2><<<dim3(16, 5, NB), 256, 0, stream>>>(
        w3, ws_g2, NV, NV, (size_t)NV * NSAMP,
        b3, nullptr, nullptr, nullptr, nullptr, out + O_VS, 0);

    view_kernel<<<(NB * NSAMP + 255) / 256, 256, 0, stream>>>(out);
}

// Round 9
// 1324.004 us; speedup vs baseline: 2.0813x; 2.0813x over previous
//
#include <hip/hip_runtime.h>
#include <math.h>

#define NB 4
#define NPTS 20000
#define NC 256
#define NV 300
#define NSAMP 1024

// d_out float offsets (outputs concatenated flat in reference return order)
#define O_GS    0         // graspness_score  [B,N]
#define O_INDS  80000     // graspable_inds   [B,NS] (as float)
#define O_XYZ   84096     // graspable_xyz    [B,NS,3]
#define O_FEAT  96384     // graspable_feats  [B,C,NS]
#define O_FP2   1144960   // fp2_graspness    [B,NS]
#define O_VS    1149056   // view_score       [B,NS,V]
#define O_TVI   2377856   // top_view_inds    [B,NS] (as float)
#define O_TVS   2381952   // top_view_scores  [B,NS]
#define O_VPX   2386048   // vp_xyz           [B,NS,3]
#define O_ROT   2398336   // vp_rot           [B,NS,3,3]

#define FPS_T 512
#define MAXPP 40     // ceil(NPTS / FPS_T)
#define LDSM  4096   // max compacted points kept in LDS

// ---------------------------------------------------------------------------
// Kernel A: fused graspable head as LDS-staged GEMM (bit-identical op order
// to the original per-point kernel). Launched once. Unchanged this round.
// ---------------------------------------------------------------------------
__global__ __launch_bounds__(256, 1) void graspness_kernel(
    const float* __restrict__ feat, const float* __restrict__ w1,
    const float* __restrict__ b1, const float* __restrict__ g1,
    const float* __restrict__ be1, const float* __restrict__ m1,
    const float* __restrict__ v1, const float* __restrict__ w2,
    const float* __restrict__ b2, float* __restrict__ out)
{
    __shared__ float Fs[NC][64];     // 64 KB: full K x 64 points
    __shared__ float Xs[NC][65];     // 66.6 KB: relu(bn(conv)) tile (+1 pad)
    __shared__ float As[2][16][64];  // 8 KB: W1 k-tile double buffer

    int b  = blockIdx.z;
    int n0 = blockIdx.x * 64;
    int tid = threadIdx.x;
    int tx = tid & 15, ty = tid >> 4;
    int rem = NPTS - n0; if (rem > 64) rem = 64;

    {
        int j  = tid & 63;
        int kb = tid >> 6;                       // 0..3
        const float* fb = feat + (size_t)b * NC * NPTS + n0;
        bool ok = (j < rem);
#pragma unroll
        for (int r = 0; r < 64; ++r) {
            int k = r * 4 + kb;
            Fs[k][j] = ok ? fb[(size_t)k * NPTS + j] : 0.f;
        }
    }

#pragma unroll
    for (int p = 0; p < 4; ++p) {
        int m_l = ty + p * 16;
        As[0][tx][m_l] = w1[(size_t)m_l * NC + tx];
    }
    __syncthreads();

    float acc[4][4][4];   // [i ch][j pt][c = k%4] -- statically indexed

    for (int s = 0; s < 64; ++s) {
        int ob = s >> 4, kt = s & 15;

        if (kt == 0) {
#pragma unroll
            for (int i = 0; i < 4; ++i)
#pragma unroll
                for (int j = 0; j < 4; ++j)
#pragma unroll
                    for (int c = 0; c < 4; ++c) acc[i][j][c] = 0.f;
        }

        if (s + 1 < 64) {
            int ob2 = (s + 1) >> 4, kt2 = (s + 1) & 15;
#pragma unroll
            for (int p = 0; p < 4; ++p) {
                int m_l = ty + p * 16;
                As[(s + 1) & 1][tx][m_l] =
                    w1[(size_t)(ob2 * 64 + m_l) * NC + kt2 * 16 + tx];
            }
        }

        const int buf = s & 1;
#pragma unroll
        for (int kk = 0; kk < 16; ++kk) {
            float4 a = *reinterpret_cast<const float4*>(&As[buf][kk][ty * 4]);
            float4 f = *reinterpret_cast<const float4*>(&Fs[kt * 16 + kk][tx * 4]);
            const int c = kk & 3;
            acc[0][0][c] += a.x * f.x; acc[0][1][c] += a.x * f.y;
            acc[0][2][c] += a.x * f.z; acc[0][3][c] += a.x * f.w;
            acc[1][0][c] += a.y * f.x; acc[1][1][c] += a.y * f.y;
            acc[1][2][c] += a.y * f.z; acc[1][3][c] += a.y * f.w;
            acc[2][0][c] += a.z * f.x; acc[2][1][c] += a.z * f.y;
            acc[2][2][c] += a.z * f.z; acc[2][3][c] += a.z * f.w;
            acc[3][0][c] += a.w * f.x; acc[3][1][c] += a.w * f.y;
            acc[3][2][c] += a.w * f.z; acc[3][3][c] += a.w * f.w;
        }

        if (kt == 15) {
#pragma unroll
            for (int i = 0; i < 4; ++i) {
                int o = ob * 64 + ty * 4 + i;
                float bo = b1[o];
                float sc = g1[o] / sqrtf(v1[o] + 1e-5f);
                float mo = m1[o], beo = be1[o];
#pragma unroll
                for (int j = 0; j < 4; ++j) {
                    float y = (acc[i][j][0] + acc[i][j][1]) +
                              (acc[i][j][2] + acc[i][j][3]) + bo;
                    float r = (y - mo) * sc + beo;
                    r = fmaxf(r, 0.f);
                    Xs[o][tx * 4 + j] = r;
                }
            }
        }
        __syncthreads();
    }

    if (tid < 64 && tid < rem) {
        float gs = 0.f;
#pragma unroll 8
        for (int o = 0; o < NC; ++o) {
            gs += w2[o] * Xs[o][tid];
        }
        out[(size_t)b * NPTS + n0 + tid] = gs + b2[0];
    }
}

// ---------------------------------------------------------------------------
// cross-lane helper
// ---------------------------------------------------------------------------
template<int CTRL>
__device__ __forceinline__ unsigned long long dpp_u64(unsigned long long x)
{
    int lo = __builtin_amdgcn_update_dpp(0, (int)(unsigned)(x & 0xffffffffull),
                                         CTRL, 0xF, 0xF, false);
    int hi = __builtin_amdgcn_update_dpp(0, (int)(unsigned)(x >> 32),
                                         CTRL, 0xF, 0xF, false);
    return ((unsigned long long)(unsigned)hi << 32) | (unsigned)lo;
}

// ---------------------------------------------------------------------------
// FPS core v5: v2's 8-wave structure with an all-DPP (VALU-only) wave reduce:
// quad_perm xor1/xor2 -> row_ror4/8 -> row_bcast15/31 -> lane 63 holds the
// wave max (ladder HW-validated in R8's run). Lane 63 writes the wave entry.
// Distance arithmetic identical (__f*_rn chain) -> same trajectory.
// ---------------------------------------------------------------------------
template<int TIER, bool USE_LDS>
__device__ __forceinline__ void fps_core2(
    int t, int M, int cnt2,
    const float* __restrict__ cxg, const float* __restrict__ cyg,
    const float* __restrict__ czg,
    const float* __restrict__ cxL, const float* __restrict__ cyL,
    const float* __restrict__ czL,
    int* __restrict__ hist, unsigned long long (*pkL)[8])
{
    int mybase = t * cnt2;
    int mycount = M - mybase;
    if (mycount > cnt2) mycount = cnt2;
    if (mycount < 0) mycount = 0;

    float rx[TIER], ry[TIER], rz[TIER], dd[TIER];
#pragma unroll
    for (int j = 0; j < TIER; ++j) {
        if (j < mycount) {
            rx[j] = USE_LDS ? cxL[mybase + j] : cxg[mybase + j];
            ry[j] = USE_LDS ? cyL[mybase + j] : cyg[mybase + j];
            rz[j] = USE_LDS ? czL[mybase + j] : czg[mybase + j];
            dd[j] = 1e10f;
        }
    }

    float wx = USE_LDS ? cxL[0] : cxg[0];
    float wy = USE_LDS ? cyL[0] : cyg[0];
    float wz = USE_LDS ? czL[0] : czg[0];
    int winner = 0;
    int w = t >> 6;

    for (int it = 0; it < NSAMP; ++it) {
        if (t == 0) hist[it] = winner;

        float bv = -2.f; int bc = 0x7fffffff;
#pragma unroll
        for (int j = 0; j < TIER; ++j) {
            if (j < mycount) {
                float dx = __fsub_rn(rx[j], wx);
                float dy = __fsub_rn(ry[j], wy);
                float dz = __fsub_rn(rz[j], wz);
                float d  = __fadd_rn(__fadd_rn(__fmul_rn(dx, dx), __fmul_rn(dy, dy)),
                                     __fmul_rn(dz, dz));
                float nd = fminf(dd[j], d);
                dd[j] = nd;
                if (nd > bv) { bv = nd; bc = mybase + j; }
            }
        }

        // packed key: value bits (>=0, unsigned-monotonic) | ~pos (min pos on ties)
        unsigned long long pk = (bc == 0x7fffffff)
            ? 0ull
            : (((unsigned long long)__float_as_uint(bv) << 32) | (unsigned)(~bc));

        // all-DPP wave max-reduce; valid in lane 63 (VALU-only, no LDS pipe)
        { unsigned long long o = dpp_u64<0xB1>(pk);  if (o > pk) pk = o; }  // quad xor1
        { unsigned long long o = dpp_u64<0x4E>(pk);  if (o > pk) pk = o; }  // quad xor2
        { unsigned long long o = dpp_u64<0x124>(pk); if (o > pk) pk = o; }  // row_ror:4
        { unsigned long long o = dpp_u64<0x128>(pk); if (o > pk) pk = o; }  // row_ror:8
        { unsigned long long o = dpp_u64<0x142>(pk); if (o > pk) pk = o; }  // row_bcast15
        { unsigned long long o = dpp_u64<0x143>(pk); if (o > pk) pk = o; }  // row_bcast31

        int par = it & 1;   // parity double-buffer -> single barrier per iter
        if ((t & 63) == 63) pkL[par][w] = pk;
        __syncthreads();

        // 8-entry tree (all threads, broadcast LDS reads)
        unsigned long long a0 = pkL[par][0], a1 = pkL[par][1];
        unsigned long long a2 = pkL[par][2], a3 = pkL[par][3];
        unsigned long long a4 = pkL[par][4], a5 = pkL[par][5];
        unsigned long long a6 = pkL[par][6], a7 = pkL[par][7];
        if (a1 > a0) a0 = a1;
        if (a3 > a2) a2 = a3;
        if (a5 > a4) a4 = a5;
        if (a7 > a6) a6 = a7;
        if (a2 > a0) a0 = a2;
        if (a6 > a4) a4 = a6;
        if (a4 > a0) a0 = a4;

        int pos = (int)(~(unsigned)(a0 & 0xffffffffull));
        winner = pos;
        wx = USE_LDS ? cxL[pos] : cxg[pos];
        wy = USE_LDS ? cyL[pos] : cyg[pos];
        wz = USE_LDS ? czL[pos] : czg[pos];
    }
}

// ---------------------------------------------------------------------------
// Kernel B: per-batch masked FPS (one workgroup per batch).
// ---------------------------------------------------------------------------
__global__ __launch_bounds__(FPS_T, 2) void fps_kernel(
    const float* __restrict__ xyz, const float* __restrict__ gs,
    float* __restrict__ out_f, int* __restrict__ out_i,
    int* __restrict__ cidx, float* __restrict__ cx,
    float* __restrict__ cy, float* __restrict__ cz)
{
    int b = blockIdx.x;
    int t = threadIdx.x;
    __shared__ int sA[FPS_T], sB[FPS_T];
    __shared__ unsigned long long pkL[2][8];
    __shared__ int hist[NSAMP];
    __shared__ float cxL[LDSM], cyL[LDSM], czL[LDSM];
    __shared__ int cidxL[LDSM];

    const float* gsb = gs + (size_t)b * NPTS;
    const float* xb  = xyz + (size_t)b * NPTS * 3;

    // ---- phase 1: count valid in my contiguous chunk ----
    int base = t * MAXPP;
    unsigned long long vmask = 0ull;
    int cnt = 0;
#pragma unroll
    for (int j = 0; j < MAXPP; ++j) {
        int p = base + j;
        if (p < NPTS) {
            if (gsb[p] > 0.09f) { vmask |= (1ull << j); ++cnt; }
        }
    }
    sA[t] = cnt;
    __syncthreads();
    // Hillis-Steele inclusive scan (ping-pong)
    int* src = sA; int* dst = sB;
    for (int off = 1; off < FPS_T; off <<= 1) {
        int v = src[t];
        if (t >= off) v += src[t - off];
        dst[t] = v;
        __syncthreads();
        int* tmp = src; src = dst; dst = tmp;
    }
    int M = src[FPS_T - 1];
    int excl = src[t] - cnt;
    bool useLds = (M <= LDSM);

    // ---- ordered compacted write (preserves index order => argmax ties OK) ----
    {
        int pos = excl;
#pragma unroll
        for (int j = 0; j < MAXPP; ++j) {
            if (vmask & (1ull << j)) {
                int p = base + j;
                if (useLds) {
                    cidxL[pos] = p;
                    cxL[pos] = xb[p * 3 + 0];
                    cyL[pos] = xb[p * 3 + 1];
                    czL[pos] = xb[p * 3 + 2];
                } else {
                    int gp = b * NPTS + pos;
                    cidx[gp] = p;
                    cx[gp] = xb[p * 3 + 0];
                    cy[gp] = xb[p * 3 + 1];
                    cz[gp] = xb[p * 3 + 2];
                }
                ++pos;
            }
        }
    }
    __syncthreads();

    if (M > 0) {
        const float* cxg = cx + b * NPTS;
        const float* cyg = cy + b * NPTS;
        const float* czg = cz + b * NPTS;

        if (useLds) {
            fps_core2<8, true>(t, M, (M + FPS_T - 1) / FPS_T, cxg, cyg, czg,
                               cxL, cyL, czL, hist, pkL);
        } else {
            int cnt2 = (M + FPS_T - 1) / FPS_T;
            if (cnt2 <= 16)      fps_core2<16, false>(t, M, cnt2, cxg, cyg, czg, cxL, cyL, czL, hist, pkL);
            else if (cnt2 <= 24) fps_core2<24, false>(t, M, cnt2, cxg, cyg, czg, cxL, cyL, czL, hist, pkL);
            else                 fps_core2<40, false>(t, M, cnt2, cxg, cyg, czg, cxL, cyL, czL, hist, pkL);
        }

        __syncthreads();
        for (int s = t; s < NSAMP; s += FPS_T) {
            int hp = hist[s];
            int oi = useLds ? cidxL[hp] : cidx[b * NPTS + hp];
            out_f[b * NSAMP + s] = (float)oi;
            out_i[b * NSAMP + s] = oi;
        }
    } else {
        for (int s = t; s < NSAMP; s += FPS_T) {
            out_f[b * NSAMP + s] = 0.f;
            out_i[b * NSAMP + s] = 0;
        }
    }
}

// ---------------------------------------------------------------------------
// gathers
// ---------------------------------------------------------------------------
__global__ void gather_xyz_kernel(const float* __restrict__ xyz,
                                  const int* __restrict__ inds,
                                  float* __restrict__ dout)
{
    int i = blockIdx.x * 256 + threadIdx.x;
    if (i >= NB * NSAMP) return;
    int b = i >> 10;
    int ind = inds[i];
    const float* p = xyz + ((size_t)b * NPTS + ind) * 3;
    dout[O_XYZ + (size_t)i * 3 + 0] = p[0];
    dout[O_XYZ + (size_t)i * 3 + 1] = p[1];
    dout[O_XYZ + (size_t)i * 3 + 2] = p[2];
    dout[O_FP2 + i] = dout[O_GS + (size_t)b * NPTS + ind];
}

__global__ void gather_feat_kernel(const float* __restrict__ feat,
                                   const int* __restrict__ inds,
                                   float* __restrict__ dout)
{
    int c = blockIdx.x, b = blockIdx.y, s = threadIdx.x;   // 1024 threads
    int ind = inds[b * NSAMP + s];
    dout[O_FEAT + ((size_t)b * NC + c) * NSAMP + s] =
        feat[((size_t)b * NC + c) * NPTS + ind];
}

// ---------------------------------------------------------------------------
// fp32 tiled GEMM: C[b] = A[M,K] x Bsrc[b][K,1024], 64x64 tile, 4x4 micro.
// EPI 0/1: +bias, BN, ReLU -> Cdst[b][c][n].  EPI 2: +bias -> d_out transposed.
// ---------------------------------------------------------------------------
template<int EPI>
__global__ __launch_bounds__(256) void gemm_epi_kernel(
    const float* __restrict__ A, const float* __restrict__ Bsrc,
    int M, int K, size_t bstride,
    const float* __restrict__ bias, const float* __restrict__ gg,
    const float* __restrict__ bb, const float* __restrict__ mm,
    const float* __restrict__ vv,
    float* __restrict__ Cdst, size_t cstride)
{
    __shared__ float As[16][68];
    __shared__ float Bs[16][68];
    int tid = threadIdx.x;
    int n0 = blockIdx.x * 64;
    int m0 = blockIdx.y * 64;
    int b  = blockIdx.z;
    const float* Bb = Bsrc + (size_t)b * bstride;
    int tx = tid & 15, ty = tid >> 4;
    float acc[4][4] = {};
    int nk = (K + 15) >> 4;
    for (int kt = 0; kt < nk; ++kt) {
        int k0 = kt * 16;
#pragma unroll
        for (int p = 0; p < 4; ++p) {   // A tile: 64 m x 16 k, transposed store
            int m_l = ty + p * 16;
            int gm = m0 + m_l, gk = k0 + tx;
            float va = (gm < M && gk < K) ? A[(size_t)gm * K + gk] : 0.f;
            As[tx][m_l] = va;
        }
#pragma unroll
        for (int p = 0; p < 4; ++p) {   // B tile: 16 k x 64 n
            int k_l = (tid >> 6) + p * 4;
            int n_l = tid & 63;
            int gk = k0 + k_l;
            float vb = (gk < K) ? Bb[(size_t)gk * NSAMP + n0 + n_l] : 0.f;
            Bs[k_l][n_l] = vb;
        }
        __syncthreads();
#pragma unroll
        for (int kk = 0; kk < 16; ++kk) {
            float a0 = As[kk][ty * 4 + 0], a1 = As[kk][ty * 4 + 1];
            float a2 = As[kk][ty * 4 + 2], a3 = As[kk][ty * 4 + 3];
            float c0 = Bs[kk][tx * 4 + 0], c1 = Bs[kk][tx * 4 + 1];
            float c2 = Bs[kk][tx * 4 + 2], c3 = Bs[kk][tx * 4 + 3];
            acc[0][0] += a0 * c0; acc[0][1] += a0 * c1; acc[0][2] += a0 * c2; acc[0][3] += a0 * c3;
            acc[1][0] += a1 * c0; acc[1][1] += a1 * c1; acc[1][2] += a1 * c2; acc[1][3] += a1 * c3;
            acc[2][0] += a2 * c0; acc[2][1] += a2 * c1; acc[2][2] += a2 * c2; acc[2][3] += a2 * c3;
            acc[3][0] += a3 * c0; acc[3][1] += a3 * c1; acc[3][2] += a3 * c2; acc[3][3] += a3 * c3;
        }
        __syncthreads();
    }
#pragma unroll
    for (int i = 0; i < 4; ++i) {
        int c = m0 + ty * 4 + i;
        if (c >= M) continue;
        float bi = bias[c];
        float scl = 0.f, sh = 0.f, mc = 0.f;
        if constexpr (EPI < 2) {
            scl = gg[c] / sqrtf(vv[c] + 1e-5f);
            sh = bb[c];
            mc = mm[c];
        }
#pragma unroll
        for (int j = 0; j < 4; ++j) {
            int n = n0 + tx * 4 + j;
            float v = acc[i][j] + bi;
            if constexpr (EPI < 2) {
                v = (v - mc) * scl + sh;
                v = fmaxf(v, 0.f);
                Cdst[(size_t)b * cstride + (size_t)c * NSAMP + n] = v;
            } else {
                Cdst[((size_t)b * NSAMP + n) * NV + c] = v;   // transposed [B,NS,V]
            }
        }
    }
}

// ---------------------------------------------------------------------------
// final: per-(b,s) argmax over 300 views, fibonacci-sphere view (f64 like numpy),
// rotation matrix (angle = 0  =>  R = [axis_x | axis_y | axis_z])
// ---------------------------------------------------------------------------
__global__ void view_kernel(float* __restrict__ dout)
{
    int i = blockIdx.x * 256 + threadIdx.x;
    if (i >= NB * NSAMP) return;
    const float* vs = dout + O_VS + (size_t)i * NV;
    float best = vs[0]; int bi = 0;
    for (int v = 1; v < NV; ++v) {
        float x = vs[v];
        if (x > best) { best = x; bi = v; }
    }
    dout[O_TVS + i] = best;
    dout[O_TVI + i] = (float)bi;

    const double PHI = (sqrt(5.0) - 1.0) / 2.0;
    double z = (2.0 * (double)bi + 1.0) / 300.0 - 1.0;
    double rr = sqrt(fmax(1.0 - z * z, 0.0));
    double ang = (2.0 * 3.14159265358979323846 * (double)bi) * PHI;
    float vx = (float)(rr * cos(ang));
    float vy = (float)(rr * sin(ang));
    float vz = (float)z;
    dout[O_VPX + (size_t)i * 3 + 0] = vx;
    dout[O_VPX + (size_t)i * 3 + 1] = vy;
    dout[O_VPX + (size_t)i * 3 + 2] = vz;

    float tx = -vx, ty = -vy, tz = -vz;
    float ayx = -ty, ayy = tx, ayz = 0.f;
    float ny = sqrtf(ayx * ayx + ayy * ayy + ayz * ayz);
    if (ny == 0.f) { ayx = 0.f; ayy = 1.f; ayz = 0.f; }
    float nx = sqrtf(tx * tx + ty * ty + tz * tz);
    float axx = tx / nx, axy = ty / nx, axz = tz / nx;
    float ny2 = sqrtf(ayx * ayx + ayy * ayy + ayz * ayz);
    ayx /= ny2; ayy /= ny2; ayz /= ny2;
    float azx = axy * ayz - axz * ayy;
    float azy = axz * ayx - axx * ayz;
    float azz = axx * ayy - axy * ayx;
    float* R = dout + O_ROT + (size_t)i * 9;
    R[0] = axx; R[1] = ayx; R[2] = azx;
    R[3] = axy; R[4] = ayy; R[5] = azy;
    R[6] = axz; R[7] = ayz; R[8] = azz;
}

// ---------------------------------------------------------------------------
extern "C" void kernel_launch(void* const* d_in, const int* in_sizes, int n_in,
                              void* d_out, int out_size, void* d_ws, size_t ws_size,
                              hipStream_t stream)
{
    const float* seed_xyz  = (const float*)d_in[0];
    const float* seed_feat = (const float*)d_in[1];
    const float* gh_w1 = (const float*)d_in[2];
    const float* gh_b1 = (const float*)d_in[3];
    const float* gh_g1 = (const float*)d_in[4];
    const float* gh_be1 = (const float*)d_in[5];
    const float* gh_m1 = (const float*)d_in[6];
    const float* gh_v1 = (const float*)d_in[7];
    const float* gh_w2 = (const float*)d_in[8];
    const float* gh_b2 = (const float*)d_in[9];
    const float* w1 = (const float*)d_in[10];
    const float* b1 = (const float*)d_in[11];
    const float* g1 = (const float*)d_in[12];
    const float* be1 = (const float*)d_in[13];
    const float* m1 = (const float*)d_in[14];
    const float* v1 = (const float*)d_in[15];
    const float* w2 = (const float*)d_in[16];
    const float* b2 = (const float*)d_in[17];
    const float* g2 = (const float*)d_in[18];
    const float* be2 = (const float*)d_in[19];
    const float* m2 = (const float*)d_in[20];
    const float* v2 = (const float*)d_in[21];
    const float* w3 = (const float*)d_in[22];
    const float* b3 = (const float*)d_in[23];

    float* out = (float*)d_out;

    // workspace layout (~10.4 MB)
    int*   ws_inds = (int*)d_ws;                     // B*NS
    int*   ws_cidx = ws_inds + NB * NSAMP;           // B*NPTS
    float* ws_cx = (float*)(ws_cidx + NB * NPTS);    // B*NPTS
    float* ws_cy = ws_cx + NB * NPTS;
    float* ws_cz = ws_cy + NB * NPTS;
    float* ws_g1 = ws_cz + NB * NPTS;                // B*256*1024
    float* ws_g2 = ws_g1 + (size_t)NB * NC * NSAMP;  // B*300*1024

    graspness_kernel<<<dim3(313, 1, NB), 256, 0, stream>>>(
        seed_feat, gh_w1, gh_b1, gh_g1, gh_be1, gh_m1, gh_v1, gh_w2, gh_b2,
        out + O_GS);

    fps_kernel<<<NB, FPS_T, 0, stream>>>(
        seed_xyz, out + O_GS, out + O_INDS, ws_inds,
        ws_cidx, ws_cx, ws_cy, ws_cz);

    gather_xyz_kernel<<<(NB * NSAMP + 255) / 256, 256, 0, stream>>>(
        seed_xyz, ws_inds, out);

    gather_feat_kernel<<<dim3(NC, NB), 1024, 0, stream>>>(
        seed_feat, ws_inds, out);

    gemm_epi_kernel<0><<<dim3(16, 4, NB), 256, 0, stream>>>(
        w1, out + O_FEAT, NC, NC, (size_t)NC * NSAMP,
        b1, g1, be1, m1, v1, ws_g1, (size_t)NC * NSAMP);

    gemm_epi_kernel<1><<<dim3(16, 5, NB), 256, 0, stream>>>(
        w2, ws_g1, NV, NC, (size_t)NC * NSAMP,
        b2, g2, be2, m2, v2, ws_g2, (size_t)NV * NSAMP);

    gemm_epi_kernel<2><<<dim3(16, 5, NB), 256, 0, stream>>>(
        w3, ws_g2, NV, NV, (size_t)NV * NSAMP,
        b3, nullptr, nullptr, nullptr, nullptr, out + O_VS, 0);

    view_kernel<<<(NB * NSAMP + 255) / 256, 256, 0, stream>>>(out);
}

// Round 10
// 1226.628 us; speedup vs baseline: 2.2465x; 1.0794x over previous
//
#include <hip/hip_runtime.h>
#include <math.h>

#define NB 4
#define NPTS 20000
#define NC 256
#define NV 300
#define NSAMP 1024

// d_out float offsets (outputs concatenated flat in reference return order)
#define O_GS    0         // graspness_score  [B,N]
#define O_INDS  80000     // graspable_inds   [B,NS] (as float)
#define O_XYZ   84096     // graspable_xyz    [B,NS,3]
#define O_FEAT  96384     // graspable_feats  [B,C,NS]
#define O_FP2   1144960   // fp2_graspness    [B,NS]
#define O_VS    1149056   // view_score       [B,NS,V]
#define O_TVI   2377856   // top_view_inds    [B,NS] (as float)
#define O_TVS   2381952   // top_view_scores  [B,NS]
#define O_VPX   2386048   // vp_xyz           [B,NS,3]
#define O_ROT   2398336   // vp_rot           [B,NS,3,3]

#define FPS_T 512
#define MAXPP 40     // ceil(NPTS / FPS_T)
#define LDSM  4096   // max compacted points kept in LDS

// ---------------------------------------------------------------------------
// Kernel A v3: fused graspable head, 512 threads (8 waves -> 2/SIMD latency
// hiding; was 4 waves = 1/SIMD, fully exposed latency). Micro 2o x 4j.
// Bit-identical numerics: each (o,j) chain still accumulates 4 partials
// keyed by k%4 in ascending k, combined (c0+c1)+(c2+c3)+b1[o]; w2-dot
// sequential over o. As padded [16][66] -> conflict-free staging writes.
// ---------------------------------------------------------------------------
__global__ __launch_bounds__(512, 2) void graspness_kernel(
    const float* __restrict__ feat, const float* __restrict__ w1,
    const float* __restrict__ b1, const float* __restrict__ g1,
    const float* __restrict__ be1, const float* __restrict__ m1,
    const float* __restrict__ v1, const float* __restrict__ w2,
    const float* __restrict__ b2, float* __restrict__ out)
{
    __shared__ float Fs[NC][64];     // 64 KB: full K x 64 points
    __shared__ float Xs[NC][65];     // 66.6 KB: relu(bn(conv)) tile (+1 pad)
    __shared__ float As[2][16][66];  // 8.4 KB: W1 k-tile double buffer, padded

    int b  = blockIdx.z;
    int n0 = blockIdx.x * 64;
    int tid = threadIdx.x;           // 0..511
    int tx = tid & 15;               // j quad: j = tx*4 + jj
    int ty = tid >> 4;               // 0..31: o pair: o = ob*64 + ty*2 + i
    int rem = NPTS - n0; if (rem > 64) rem = 64;

    // ---- load F tile [256 k][64 n] with 512 threads ----
    {
        int j  = tid & 63;
        int kb = tid >> 6;                       // 0..7
        const float* fb = feat + (size_t)b * NC * NPTS + n0;
        bool ok = (j < rem);
#pragma unroll
        for (int r = 0; r < 32; ++r) {
            int k = r * 8 + kb;
            Fs[k][j] = ok ? fb[(size_t)k * NPTS + j] : 0.f;
        }
    }

    // ---- stage s=0 (ob=0, kt=0): As[k][o] = w1[o*NC + k], 2 elems/thread ----
    {
        int k_l = tid & 15;
        int o_l = tid >> 4;          // 0..31
        As[0][k_l][o_l]      = w1[(size_t)o_l * NC + k_l];
        As[0][k_l][o_l + 32] = w1[(size_t)(o_l + 32) * NC + k_l];
    }
    __syncthreads();

    float acc[2][4][4];   // [i o][j pt][c = k%4] -- statically indexed

    for (int s = 0; s < 64; ++s) {
        int ob = s >> 4, kt = s & 15;

        if (kt == 0) {
#pragma unroll
            for (int i = 0; i < 2; ++i)
#pragma unroll
                for (int j = 0; j < 4; ++j)
#pragma unroll
                    for (int c = 0; c < 4; ++c) acc[i][j][c] = 0.f;
        }

        if (s + 1 < 64) {
            int ob2 = (s + 1) >> 4, kt2 = (s + 1) & 15;
            int k_l = tid & 15;
            int o_l = tid >> 4;
            As[(s + 1) & 1][k_l][o_l] =
                w1[(size_t)(ob2 * 64 + o_l) * NC + kt2 * 16 + k_l];
            As[(s + 1) & 1][k_l][o_l + 32] =
                w1[(size_t)(ob2 * 64 + o_l + 32) * NC + kt2 * 16 + k_l];
        }

        const int buf = s & 1;
#pragma unroll
        for (int kk = 0; kk < 16; ++kk) {
            float2 a = *reinterpret_cast<const float2*>(&As[buf][kk][ty * 2]);
            float4 f = *reinterpret_cast<const float4*>(&Fs[kt * 16 + kk][tx * 4]);
            const int c = kk & 3;
            acc[0][0][c] += a.x * f.x; acc[0][1][c] += a.x * f.y;
            acc[0][2][c] += a.x * f.z; acc[0][3][c] += a.x * f.w;
            acc[1][0][c] += a.y * f.x; acc[1][1][c] += a.y * f.y;
            acc[1][2][c] += a.y * f.z; acc[1][3][c] += a.y * f.w;
        }

        if (kt == 15) {
#pragma unroll
            for (int i = 0; i < 2; ++i) {
                int o = ob * 64 + ty * 2 + i;
                float bo = b1[o];
                float sc = g1[o] / sqrtf(v1[o] + 1e-5f);
                float mo = m1[o], beo = be1[o];
#pragma unroll
                for (int j = 0; j < 4; ++j) {
                    float y = (acc[i][j][0] + acc[i][j][1]) +
                              (acc[i][j][2] + acc[i][j][3]) + bo;
                    float r = (y - mo) * sc + beo;
                    r = fmaxf(r, 0.f);
                    Xs[o][tx * 4 + j] = r;
                }
            }
        }
        __syncthreads();
    }

    // ---- w2 dot: sequential over o = 0..255, same order as before ----
    if (tid < 64 && tid < rem) {
        float gs = 0.f;
#pragma unroll 8
        for (int o = 0; o < NC; ++o) {
            gs += w2[o] * Xs[o][tid];
        }
        out[(size_t)b * NPTS + n0 + tid] = gs + b2[0];
    }
}

// ---------------------------------------------------------------------------
// cross-lane helper
// ---------------------------------------------------------------------------
template<int CTRL>
__device__ __forceinline__ unsigned long long dpp_u64(unsigned long long x)
{
    int lo = __builtin_amdgcn_update_dpp(0, (int)(unsigned)(x & 0xffffffffull),
                                         CTRL, 0xF, 0xF, false);
    int hi = __builtin_amdgcn_update_dpp(0, (int)(unsigned)(x >> 32),
                                         CTRL, 0xF, 0xF, false);
    return ((unsigned long long)(unsigned)hi << 32) | (unsigned)lo;
}

// ---------------------------------------------------------------------------
// FPS core v5 (unchanged from R9; measured 738 us): 8-wave structure, all-DPP
// wave reduce to lane 63, 8-entry LDS tree, parity double-buffer.
// ---------------------------------------------------------------------------
template<int TIER, bool USE_LDS>
__device__ __forceinline__ void fps_core2(
    int t, int M, int cnt2,
    const float* __restrict__ cxg, const float* __restrict__ cyg,
    const float* __restrict__ czg,
    const float* __restrict__ cxL, const float* __restrict__ cyL,
    const float* __restrict__ czL,
    int* __restrict__ hist, unsigned long long (*pkL)[8])
{
    int mybase = t * cnt2;
    int mycount = M - mybase;
    if (mycount > cnt2) mycount = cnt2;
    if (mycount < 0) mycount = 0;

    float rx[TIER], ry[TIER], rz[TIER], dd[TIER];
#pragma unroll
    for (int j = 0; j < TIER; ++j) {
        if (j < mycount) {
            rx[j] = USE_LDS ? cxL[mybase + j] : cxg[mybase + j];
            ry[j] = USE_LDS ? cyL[mybase + j] : cyg[mybase + j];
            rz[j] = USE_LDS ? czL[mybase + j] : czg[mybase + j];
            dd[j] = 1e10f;
        }
    }

    float wx = USE_LDS ? cxL[0] : cxg[0];
    float wy = USE_LDS ? cyL[0] : cyg[0];
    float wz = USE_LDS ? czL[0] : czg[0];
    int winner = 0;
    int w = t >> 6;

    for (int it = 0; it < NSAMP; ++it) {
        if (t == 0) hist[it] = winner;

        float bv = -2.f; int bc = 0x7fffffff;
#pragma unroll
        for (int j = 0; j < TIER; ++j) {
            if (j < mycount) {
                float dx = __fsub_rn(rx[j], wx);
                float dy = __fsub_rn(ry[j], wy);
                float dz = __fsub_rn(rz[j], wz);
                float d  = __fadd_rn(__fadd_rn(__fmul_rn(dx, dx), __fmul_rn(dy, dy)),
                                     __fmul_rn(dz, dz));
                float nd = fminf(dd[j], d);
                dd[j] = nd;
                if (nd > bv) { bv = nd; bc = mybase + j; }
            }
        }

        // packed key: value bits (>=0, unsigned-monotonic) | ~pos (min pos on ties)
        unsigned long long pk = (bc == 0x7fffffff)
            ? 0ull
            : (((unsigned long long)__float_as_uint(bv) << 32) | (unsigned)(~bc));

        // all-DPP wave max-reduce; valid in lane 63 (VALU-only, no LDS pipe)
        { unsigned long long o = dpp_u64<0xB1>(pk);  if (o > pk) pk = o; }  // quad xor1
        { unsigned long long o = dpp_u64<0x4E>(pk);  if (o > pk) pk = o; }  // quad xor2
        { unsigned long long o = dpp_u64<0x124>(pk); if (o > pk) pk = o; }  // row_ror:4
        { unsigned long long o = dpp_u64<0x128>(pk); if (o > pk) pk = o; }  // row_ror:8
        { unsigned long long o = dpp_u64<0x142>(pk); if (o > pk) pk = o; }  // row_bcast15
        { unsigned long long o = dpp_u64<0x143>(pk); if (o > pk) pk = o; }  // row_bcast31

        int par = it & 1;   // parity double-buffer -> single barrier per iter
        if ((t & 63) == 63) pkL[par][w] = pk;
        __syncthreads();

        // 8-entry tree (all threads, broadcast LDS reads)
        unsigned long long a0 = pkL[par][0], a1 = pkL[par][1];
        unsigned long long a2 = pkL[par][2], a3 = pkL[par][3];
        unsigned long long a4 = pkL[par][4], a5 = pkL[par][5];
        unsigned long long a6 = pkL[par][6], a7 = pkL[par][7];
        if (a1 > a0) a0 = a1;
        if (a3 > a2) a2 = a3;
        if (a5 > a4) a4 = a5;
        if (a7 > a6) a6 = a7;
        if (a2 > a0) a0 = a2;
        if (a6 > a4) a4 = a6;
        if (a4 > a0) a0 = a4;

        int pos = (int)(~(unsigned)(a0 & 0xffffffffull));
        winner = pos;
        wx = USE_LDS ? cxL[pos] : cxg[pos];
        wy = USE_LDS ? cyL[pos] : cyg[pos];
        wz = USE_LDS ? czL[pos] : czg[pos];
    }
}

// ---------------------------------------------------------------------------
// Kernel B: per-batch masked FPS (one workgroup per batch). Unchanged.
// ---------------------------------------------------------------------------
__global__ __launch_bounds__(FPS_T, 2) void fps_kernel(
    const float* __restrict__ xyz, const float* __restrict__ gs,
    float* __restrict__ out_f, int* __restrict__ out_i,
    int* __restrict__ cidx, float* __restrict__ cx,
    float* __restrict__ cy, float* __restrict__ cz)
{
    int b = blockIdx.x;
    int t = threadIdx.x;
    __shared__ int sA[FPS_T], sB[FPS_T];
    __shared__ unsigned long long pkL[2][8];
    __shared__ int hist[NSAMP];
    __shared__ float cxL[LDSM], cyL[LDSM], czL[LDSM];
    __shared__ int cidxL[LDSM];

    const float* gsb = gs + (size_t)b * NPTS;
    const float* xb  = xyz + (size_t)b * NPTS * 3;

    // ---- phase 1: count valid in my contiguous chunk ----
    int base = t * MAXPP;
    unsigned long long vmask = 0ull;
    int cnt = 0;
#pragma unroll
    for (int j = 0; j < MAXPP; ++j) {
        int p = base + j;
        if (p < NPTS) {
            if (gsb[p] > 0.09f) { vmask |= (1ull << j); ++cnt; }
        }
    }
    sA[t] = cnt;
    __syncthreads();
    // Hillis-Steele inclusive scan (ping-pong)
    int* src = sA; int* dst = sB;
    for (int off = 1; off < FPS_T; off <<= 1) {
        int v = src[t];
        if (t >= off) v += src[t - off];
        dst[t] = v;
        __syncthreads();
        int* tmp = src; src = dst; dst = tmp;
    }
    int M = src[FPS_T - 1];
    int excl = src[t] - cnt;
    bool useLds = (M <= LDSM);

    // ---- ordered compacted write (preserves index order => argmax ties OK) ----
    {
        int pos = excl;
#pragma unroll
        for (int j = 0; j < MAXPP; ++j) {
            if (vmask & (1ull << j)) {
                int p = base + j;
                if (useLds) {
                    cidxL[pos] = p;
                    cxL[pos] = xb[p * 3 + 0];
                    cyL[pos] = xb[p * 3 + 1];
                    czL[pos] = xb[p * 3 + 2];
                } else {
                    int gp = b * NPTS + pos;
                    cidx[gp] = p;
                    cx[gp] = xb[p * 3 + 0];
                    cy[gp] = xb[p * 3 + 1];
                    cz[gp] = xb[p * 3 + 2];
                }
                ++pos;
            }
        }
    }
    __syncthreads();

    if (M > 0) {
        const float* cxg = cx + b * NPTS;
        const float* cyg = cy + b * NPTS;
        const float* czg = cz + b * NPTS;

        if (useLds) {
            fps_core2<8, true>(t, M, (M + FPS_T - 1) / FPS_T, cxg, cyg, czg,
                               cxL, cyL, czL, hist, pkL);
        } else {
            int cnt2 = (M + FPS_T - 1) / FPS_T;
            if (cnt2 <= 16)      fps_core2<16, false>(t, M, cnt2, cxg, cyg, czg, cxL, cyL, czL, hist, pkL);
            else if (cnt2 <= 24) fps_core2<24, false>(t, M, cnt2, cxg, cyg, czg, cxL, cyL, czL, hist, pkL);
            else                 fps_core2<40, false>(t, M, cnt2, cxg, cyg, czg, cxL, cyL, czL, hist, pkL);
        }

        __syncthreads();
        for (int s = t; s < NSAMP; s += FPS_T) {
            int hp = hist[s];
            int oi = useLds ? cidxL[hp] : cidx[b * NPTS + hp];
            out_f[b * NSAMP + s] = (float)oi;
            out_i[b * NSAMP + s] = oi;
        }
    } else {
        for (int s = t; s < NSAMP; s += FPS_T) {
            out_f[b * NSAMP + s] = 0.f;
            out_i[b * NSAMP + s] = 0;
        }
    }
}

// ---------------------------------------------------------------------------
// gathers
// ---------------------------------------------------------------------------
__global__ void gather_xyz_kernel(const float* __restrict__ xyz,
                                  const int* __restrict__ inds,
                                  float* __restrict__ dout)
{
    int i = blockIdx.x * 256 + threadIdx.x;
    if (i >= NB * NSAMP) return;
    int b = i >> 10;
    int ind = inds[i];
    const float* p = xyz + ((size_t)b * NPTS + ind) * 3;
    dout[O_XYZ + (size_t)i * 3 + 0] = p[0];
    dout[O_XYZ + (size_t)i * 3 + 1] = p[1];
    dout[O_XYZ + (size_t)i * 3 + 2] = p[2];
    dout[O_FP2 + i] = dout[O_GS + (size_t)b * NPTS + ind];
}

__global__ void gather_feat_kernel(const float* __restrict__ feat,
                                   const int* __restrict__ inds,
                                   float* __restrict__ dout)
{
    int c = blockIdx.x, b = blockIdx.y, s = threadIdx.x;   // 1024 threads
    int ind = inds[b * NSAMP + s];
    dout[O_FEAT + ((size_t)b * NC + c) * NSAMP + s] =
        feat[((size_t)b * NC + c) * NPTS + ind];
}

// ---------------------------------------------------------------------------
// fp32 tiled GEMM: C[b] = A[M,K] x Bsrc[b][K,1024], 64x64 tile, 4x4 micro.
// EPI 0/1: +bias, BN, ReLU -> Cdst[b][c][n].
// EPI 2:   +bias -> d_out transposed [B,NS,V] via LDS-staged coalesced store.
// ---------------------------------------------------------------------------
template<int EPI>
__global__ __launch_bounds__(256) void gemm_epi_kernel(
    const float* __restrict__ A, const float* __restrict__ Bsrc,
    int M, int K, size_t bstride,
    const float* __restrict__ bias, const float* __restrict__ gg,
    const float* __restrict__ bb, const float* __restrict__ mm,
    const float* __restrict__ vv,
    float* __restrict__ Cdst, size_t cstride)
{
    __shared__ float As[16][68];
    __shared__ float Bs[16][68];
    __shared__ float Cs[64][65];   // EPI2 transpose staging (unused otherwise)
    int tid = threadIdx.x;
    int n0 = blockIdx.x * 64;
    int m0 = blockIdx.y * 64;
    int b  = blockIdx.z;
    const float* Bb = Bsrc + (size_t)b * bstride;
    int tx = tid & 15, ty = tid >> 4;
    float acc[4][4] = {};
    int nk = (K + 15) >> 4;
    for (int kt = 0; kt < nk; ++kt) {
        int k0 = kt * 16;
#pragma unroll
        for (int p = 0; p < 4; ++p) {   // A tile: 64 m x 16 k, transposed store
            int m_l = ty + p * 16;
            int gm = m0 + m_l, gk = k0 + tx;
            float va = (gm < M && gk < K) ? A[(size_t)gm * K + gk] : 0.f;
            As[tx][m_l] = va;
        }
#pragma unroll
        for (int p = 0; p < 4; ++p) {   // B tile: 16 k x 64 n
            int k_l = (tid >> 6) + p * 4;
            int n_l = tid & 63;
            int gk = k0 + k_l;
            float vb = (gk < K) ? Bb[(size_t)gk * NSAMP + n0 + n_l] : 0.f;
            Bs[k_l][n_l] = vb;
        }
        __syncthreads();
#pragma unroll
        for (int kk = 0; kk < 16; ++kk) {
            float a0 = As[kk][ty * 4 + 0], a1 = As[kk][ty * 4 + 1];
            float a2 = As[kk][ty * 4 + 2], a3 = As[kk][ty * 4 + 3];
            float c0 = Bs[kk][tx * 4 + 0], c1 = Bs[kk][tx * 4 + 1];
            float c2 = Bs[kk][tx * 4 + 2], c3 = Bs[kk][tx * 4 + 3];
            acc[0][0] += a0 * c0; acc[0][1] += a0 * c1; acc[0][2] += a0 * c2; acc[0][3] += a0 * c3;
            acc[1][0] += a1 * c0; acc[1][1] += a1 * c1; acc[1][2] += a1 * c2; acc[1][3] += a1 * c3;
            acc[2][0] += a2 * c0; acc[2][1] += a2 * c1; acc[2][2] += a2 * c2; acc[2][3] += a2 * c3;
            acc[3][0] += a3 * c0; acc[3][1] += a3 * c1; acc[3][2] += a3 * c2; acc[3][3] += a3 * c3;
        }
        __syncthreads();
    }
#pragma unroll
    for (int i = 0; i < 4; ++i) {
        int c = m0 + ty * 4 + i;
        if (c >= M) continue;
        float bi = bias[c];
        float scl = 0.f, sh = 0.f, mc = 0.f;
        if constexpr (EPI < 2) {
            scl = gg[c] / sqrtf(vv[c] + 1e-5f);
            sh = bb[c];
            mc = mm[c];
        }
#pragma unroll
        for (int j = 0; j < 4; ++j) {
            int n = n0 + tx * 4 + j;
            float v = acc[i][j] + bi;
            if constexpr (EPI < 2) {
                v = (v - mc) * scl + sh;
                v = fmaxf(v, 0.f);
                Cdst[(size_t)b * cstride + (size_t)c * NSAMP + n] = v;
            } else {
                Cs[ty * 4 + i][tx * 4 + j] = v;   // stage for coalesced store
            }
        }
    }
    if constexpr (EPI == 2) {
        __syncthreads();
        for (int idx = tid; idx < 64 * 64; idx += 256) {
            int n_l = idx >> 6, c_l = idx & 63;
            int c = m0 + c_l;
            if (c < M)
                Cdst[((size_t)b * NSAMP + n0 + n_l) * NV + c] = Cs[c_l][n_l];
        }
    }
}

// ---------------------------------------------------------------------------
// final: per-(b,s) argmax over 300 views, fibonacci-sphere view (f64 like numpy),
// rotation matrix (angle = 0  =>  R = [axis_x | axis_y | axis_z])
// ---------------------------------------------------------------------------
__global__ void view_kernel(float* __restrict__ dout)
{
    int i = blockIdx.x * 256 + threadIdx.x;
    if (i >= NB * NSAMP) return;
    const float* vs = dout + O_VS + (size_t)i * NV;
    float best = vs[0]; int bi = 0;
    for (int v = 1; v < NV; ++v) {
        float x = vs[v];
        if (x > best) { best = x; bi = v; }
    }
    dout[O_TVS + i] = best;
    dout[O_TVI + i] = (float)bi;

    const double PHI = (sqrt(5.0) - 1.0) / 2.0;
    double z = (2.0 * (double)bi + 1.0) / 300.0 - 1.0;
    double rr = sqrt(fmax(1.0 - z * z, 0.0));
    double ang = (2.0 * 3.14159265358979323846 * (double)bi) * PHI;
    float vx = (float)(rr * cos(ang));
    float vy = (float)(rr * sin(ang));
    float vz = (float)z;
    dout[O_VPX + (size_t)i * 3 + 0] = vx;
    dout[O_VPX + (size_t)i * 3 + 1] = vy;
    dout[O_VPX + (size_t)i * 3 + 2] = vz;

    float tx = -vx, ty = -vy, tz = -vz;
    float ayx = -ty, ayy = tx, ayz = 0.f;
    float ny = sqrtf(ayx * ayx + ayy * ayy + ayz * ayz);
    if (ny == 0.f) { ayx = 0.f; ayy = 1.f; ayz = 0.f; }
    float nx = sqrtf(tx * tx + ty * ty + tz * tz);
    float axx = tx / nx, axy = ty / nx, axz = tz / nx;
    float ny2 = sqrtf(ayx * ayx + ayy * ayy + ayz * ayz);
    ayx /= ny2; ayy /= ny2; ayz /= ny2;
    float azx = axy * ayz - axz * ayy;
    float azy = axz * ayx - axx * ayz;
    float azz = axx * ayy - axy * ayx;
    float* R = dout + O_ROT + (size_t)i * 9;
    R[0] = axx; R[1] = ayx; R[2] = azx;
    R[3] = axy; R[4] = ayy; R[5] = azy;
    R[6] = axz; R[7] = ayz; R[8] = azz;
}

// ---------------------------------------------------------------------------
extern "C" void kernel_launch(void* const* d_in, const int* in_sizes, int n_in,
                              void* d_out, int out_size, void* d_ws, size_t ws_size,
                              hipStream_t stream)
{
    const float* seed_xyz  = (const float*)d_in[0];
    const float* seed_feat = (const float*)d_in[1];
    const float* gh_w1 = (const float*)d_in[2];
    const float* gh_b1 = (const float*)d_in[3];
    const float* gh_g1 = (const float*)d_in[4];
    const float* gh_be1 = (const float*)d_in[5];
    const float* gh_m1 = (const float*)d_in[6];
    const float* gh_v1 = (const float*)d_in[7];
    const float* gh_w2 = (const float*)d_in[8];
    const float* gh_b2 = (const float*)d_in[9];
    const float* w1 = (const float*)d_in[10];
    const float* b1 = (const float*)d_in[11];
    const float* g1 = (const float*)d_in[12];
    const float* be1 = (const float*)d_in[13];
    const float* m1 = (const float*)d_in[14];
    const float* v1 = (const float*)d_in[15];
    const float* w2 = (const float*)d_in[16];
    const float* b2 = (const float*)d_in[17];
    const float* g2 = (const float*)d_in[18];
    const float* be2 = (const float*)d_in[19];
    const float* m2 = (const float*)d_in[20];
    const float* v2 = (const float*)d_in[21];
    const float* w3 = (const float*)d_in[22];
    const float* b3 = (const float*)d_in[23];

    float* out = (float*)d_out;

    // workspace layout (~10.4 MB)
    int*   ws_inds = (int*)d_ws;                     // B*NS
    int*   ws_cidx = ws_inds + NB * NSAMP;           // B*NPTS
    float* ws_cx = (float*)(ws_cidx + NB * NPTS);    // B*NPTS
    float* ws_cy = ws_cx + NB * NPTS;
    float* ws_cz = ws_cy + NB * NPTS;
    float* ws_g1 = ws_cz + NB * NPTS;                // B*256*1024
    float* ws_g2 = ws_g1 + (size_t)NB * NC * NSAMP;  // B*300*1024

    graspness_kernel<<<dim3(313, 1, NB), 512, 0, stream>>>(
        seed_feat, gh_w1, gh_b1, gh_g1, gh_be1, gh_m1, gh_v1, gh_w2, gh_b2,
        out + O_GS);

    fps_kernel<<<NB, FPS_T, 0, stream>>>(
        seed_xyz, out + O_GS, out + O_INDS, ws_inds,
        ws_cidx, ws_cx, ws_cy, ws_cz);

    gather_xyz_kernel<<<(NB * NSAMP + 255) / 256, 256, 0, stream>>>(
        seed_xyz, ws_inds, out);

    gather_feat_kernel<<<dim3(NC, NB), 1024, 0, stream>>>(
        seed_feat, ws_inds, out);

    gemm_epi_kernel<0><<<dim3(16, 4, NB), 256, 0, stream>>>(
        w1, out + O_FEAT, NC, NC, (size_t)NC * NSAMP,
        b1, g1, be1, m1, v1, ws_g1, (size_t)NC * NSAMP);

    gemm_epi_kernel<1><<<dim3(16, 5, NB), 256, 0, stream>>>(
        w2, ws_g1, NV, NC, (size_t)NC * NSAMP,
        b2, g2, be2, m2, v2, ws_g2, (size_t)NV * NSAMP);

    gemm_epi_kernel<2><<<dim3(16, 5, NB), 256, 0, stream>>>(
        w3, ws_g2, NV, NV, (size_t)NV * NSAMP,
        b3, nullptr, nullptr, nullptr, nullptr, out + O_VS, 0);

    view_kernel<<<(NB * NSAMP + 255) / 256, 256, 0, stream>>>(out);
}

// Round 11
// 1201.960 us; speedup vs baseline: 2.2926x; 1.0205x over previous
//
#include <hip/hip_runtime.h>
#include <math.h>

#define NB 4
#define NPTS 20000
#define NC 256
#define NV 300
#define NSAMP 1024

// d_out float offsets (outputs concatenated flat in reference return order)
#define O_GS    0         // graspness_score  [B,N]
#define O_INDS  80000     // graspable_inds   [B,NS] (as float)
#define O_XYZ   84096     // graspable_xyz    [B,NS,3]
#define O_FEAT  96384     // graspable_feats  [B,C,NS]
#define O_FP2   1144960   // fp2_graspness    [B,NS]
#define O_VS    1149056   // view_score       [B,NS,V]
#define O_TVI   2377856   // top_view_inds    [B,NS] (as float)
#define O_TVS   2381952   // top_view_scores  [B,NS]
#define O_VPX   2386048   // vp_xyz           [B,NS,3]
#define O_ROT   2398336   // vp_rot           [B,NS,3,3]

#define FPS_T 512
#define MAXPP 40     // ceil(NPTS / FPS_T)
#define LDSM  4096   // max compacted points kept in LDS

// ---------------------------------------------------------------------------
// Kernel A v4: fused graspable head, 512 threads, T14 async-stage split:
// W1 staging values loaded to REGISTERS before the compute loop, ds_write
// AFTER compute (just before the barrier) -> HBM latency hides under FMAs.
// Numerics bit-identical (same 4-partial k%4 chains, same combine, same
// sequential w2-dot).
// ---------------------------------------------------------------------------
__global__ __launch_bounds__(512, 2) void graspness_kernel(
    const float* __restrict__ feat, const float* __restrict__ w1,
    const float* __restrict__ b1, const float* __restrict__ g1,
    const float* __restrict__ be1, const float* __restrict__ m1,
    const float* __restrict__ v1, const float* __restrict__ w2,
    const float* __restrict__ b2, float* __restrict__ out)
{
    __shared__ float Fs[NC][64];     // 64 KB: full K x 64 points
    __shared__ float Xs[NC][65];     // 66.6 KB: relu(bn(conv)) tile (+1 pad)
    __shared__ float As[2][16][66];  // 8.4 KB: W1 k-tile double buffer, padded

    int b  = blockIdx.z;
    int n0 = blockIdx.x * 64;
    int tid = threadIdx.x;           // 0..511
    int tx = tid & 15;               // j quad: j = tx*4 + jj
    int ty = tid >> 4;               // 0..31: o pair: o = ob*64 + ty*2 + i
    int k_l = tid & 15;              // staging k within tile
    int o_l = tid >> 4;              // staging o (0..31)
    int rem = NPTS - n0; if (rem > 64) rem = 64;

    // ---- load F tile [256 k][64 n] with 512 threads ----
    {
        int j  = tid & 63;
        int kb = tid >> 6;                       // 0..7
        const float* fb = feat + (size_t)b * NC * NPTS + n0;
        bool ok = (j < rem);
#pragma unroll
        for (int r = 0; r < 32; ++r) {
            int k = r * 8 + kb;
            Fs[k][j] = ok ? fb[(size_t)k * NPTS + j] : 0.f;
        }
    }

    // ---- stage s=0 (ob=0, kt=0) ----
    As[0][k_l][o_l]      = w1[(size_t)o_l * NC + k_l];
    As[0][k_l][o_l + 32] = w1[(size_t)(o_l + 32) * NC + k_l];
    __syncthreads();

    float acc[2][4][4];   // [i o][j pt][c = k%4] -- statically indexed

    for (int s = 0; s < 64; ++s) {
        int ob = s >> 4, kt = s & 15;

        if (kt == 0) {
#pragma unroll
            for (int i = 0; i < 2; ++i)
#pragma unroll
                for (int j = 0; j < 4; ++j)
#pragma unroll
                    for (int c = 0; c < 4; ++c) acc[i][j][c] = 0.f;
        }

        // T14: issue next-tile loads into registers BEFORE compute
        float st0 = 0.f, st1 = 0.f;
        if (s + 1 < 64) {
            int ob2 = (s + 1) >> 4, kt2 = (s + 1) & 15;
            st0 = w1[(size_t)(ob2 * 64 + o_l) * NC + kt2 * 16 + k_l];
            st1 = w1[(size_t)(ob2 * 64 + o_l + 32) * NC + kt2 * 16 + k_l];
        }

        const int buf = s & 1;
#pragma unroll
        for (int kk = 0; kk < 16; ++kk) {
            float2 a = *reinterpret_cast<const float2*>(&As[buf][kk][ty * 2]);
            float4 f = *reinterpret_cast<const float4*>(&Fs[kt * 16 + kk][tx * 4]);
            const int c = kk & 3;
            acc[0][0][c] += a.x * f.x; acc[0][1][c] += a.x * f.y;
            acc[0][2][c] += a.x * f.z; acc[0][3][c] += a.x * f.w;
            acc[1][0][c] += a.y * f.x; acc[1][1][c] += a.y * f.y;
            acc[1][2][c] += a.y * f.z; acc[1][3][c] += a.y * f.w;
        }

        if (kt == 15) {
#pragma unroll
            for (int i = 0; i < 2; ++i) {
                int o = ob * 64 + ty * 2 + i;
                float bo = b1[o];
                float sc = g1[o] / sqrtf(v1[o] + 1e-5f);
                float mo = m1[o], beo = be1[o];
#pragma unroll
                for (int j = 0; j < 4; ++j) {
                    float y = (acc[i][j][0] + acc[i][j][1]) +
                              (acc[i][j][2] + acc[i][j][3]) + bo;
                    float r = (y - mo) * sc + beo;
                    r = fmaxf(r, 0.f);
                    Xs[o][tx * 4 + j] = r;
                }
            }
        }

        // T14: LDS writes AFTER compute (latency already hidden)
        if (s + 1 < 64) {
            As[(s + 1) & 1][k_l][o_l]      = st0;
            As[(s + 1) & 1][k_l][o_l + 32] = st1;
        }
        __syncthreads();
    }

    // ---- w2 dot: sequential over o = 0..255, same order as before ----
    if (tid < 64 && tid < rem) {
        float gs = 0.f;
#pragma unroll 8
        for (int o = 0; o < NC; ++o) {
            gs += w2[o] * Xs[o][tid];
        }
        out[(size_t)b * NPTS + n0 + tid] = gs + b2[0];
    }
}

// ---------------------------------------------------------------------------
// cross-lane helper
// ---------------------------------------------------------------------------
template<int CTRL>
__device__ __forceinline__ unsigned long long dpp_u64(unsigned long long x)
{
    int lo = __builtin_amdgcn_update_dpp(0, (int)(unsigned)(x & 0xffffffffull),
                                         CTRL, 0xF, 0xF, false);
    int hi = __builtin_amdgcn_update_dpp(0, (int)(unsigned)(x >> 32),
                                         CTRL, 0xF, 0xF, false);
    return ((unsigned long long)(unsigned)hi << 32) | (unsigned)lo;
}

// ---------------------------------------------------------------------------
// FPS core v5 (frozen; measured 738 us): 8-wave structure, all-DPP wave
// reduce to lane 63, 8-entry LDS tree, parity double-buffer.
// ---------------------------------------------------------------------------
template<int TIER, bool USE_LDS>
__device__ __forceinline__ void fps_core2(
    int t, int M, int cnt2,
    const float* __restrict__ cxg, const float* __restrict__ cyg,
    const float* __restrict__ czg,
    const float* __restrict__ cxL, const float* __restrict__ cyL,
    const float* __restrict__ czL,
    int* __restrict__ hist, unsigned long long (*pkL)[8])
{
    int mybase = t * cnt2;
    int mycount = M - mybase;
    if (mycount > cnt2) mycount = cnt2;
    if (mycount < 0) mycount = 0;

    float rx[TIER], ry[TIER], rz[TIER], dd[TIER];
#pragma unroll
    for (int j = 0; j < TIER; ++j) {
        if (j < mycount) {
            rx[j] = USE_LDS ? cxL[mybase + j] : cxg[mybase + j];
            ry[j] = USE_LDS ? cyL[mybase + j] : cyg[mybase + j];
            rz[j] = USE_LDS ? czL[mybase + j] : czg[mybase + j];
            dd[j] = 1e10f;
        }
    }

    float wx = USE_LDS ? cxL[0] : cxg[0];
    float wy = USE_LDS ? cyL[0] : cyg[0];
    float wz = USE_LDS ? czL[0] : czg[0];
    int winner = 0;
    int w = t >> 6;

    for (int it = 0; it < NSAMP; ++it) {
        if (t == 0) hist[it] = winner;

        float bv = -2.f; int bc = 0x7fffffff;
#pragma unroll
        for (int j = 0; j < TIER; ++j) {
            if (j < mycount) {
                float dx = __fsub_rn(rx[j], wx);
                float dy = __fsub_rn(ry[j], wy);
                float dz = __fsub_rn(rz[j], wz);
                float d  = __fadd_rn(__fadd_rn(__fmul_rn(dx, dx), __fmul_rn(dy, dy)),
                                     __fmul_rn(dz, dz));
                float nd = fminf(dd[j], d);
                dd[j] = nd;
                if (nd > bv) { bv = nd; bc = mybase + j; }
            }
        }

        // packed key: value bits (>=0, unsigned-monotonic) | ~pos (min pos on ties)
        unsigned long long pk = (bc == 0x7fffffff)
            ? 0ull
            : (((unsigned long long)__float_as_uint(bv) << 32) | (unsigned)(~bc));

        // all-DPP wave max-reduce; valid in lane 63 (VALU-only, no LDS pipe)
        { unsigned long long o = dpp_u64<0xB1>(pk);  if (o > pk) pk = o; }  // quad xor1
        { unsigned long long o = dpp_u64<0x4E>(pk);  if (o > pk) pk = o; }  // quad xor2
        { unsigned long long o = dpp_u64<0x124>(pk); if (o > pk) pk = o; }  // row_ror:4
        { unsigned long long o = dpp_u64<0x128>(pk); if (o > pk) pk = o; }  // row_ror:8
        { unsigned long long o = dpp_u64<0x142>(pk); if (o > pk) pk = o; }  // row_bcast15
        { unsigned long long o = dpp_u64<0x143>(pk); if (o > pk) pk = o; }  // row_bcast31

        int par = it & 1;   // parity double-buffer -> single barrier per iter
        if ((t & 63) == 63) pkL[par][w] = pk;
        __syncthreads();

        // 8-entry tree (all threads, broadcast LDS reads)
        unsigned long long a0 = pkL[par][0], a1 = pkL[par][1];
        unsigned long long a2 = pkL[par][2], a3 = pkL[par][3];
        unsigned long long a4 = pkL[par][4], a5 = pkL[par][5];
        unsigned long long a6 = pkL[par][6], a7 = pkL[par][7];
        if (a1 > a0) a0 = a1;
        if (a3 > a2) a2 = a3;
        if (a5 > a4) a4 = a5;
        if (a7 > a6) a6 = a7;
        if (a2 > a0) a0 = a2;
        if (a6 > a4) a4 = a6;
        if (a4 > a0) a0 = a4;

        int pos = (int)(~(unsigned)(a0 & 0xffffffffull));
        winner = pos;
        wx = USE_LDS ? cxL[pos] : cxg[pos];
        wy = USE_LDS ? cyL[pos] : cyg[pos];
        wz = USE_LDS ? czL[pos] : czg[pos];
    }
}

// ---------------------------------------------------------------------------
// Kernel B: per-batch masked FPS (one workgroup per batch). Unchanged.
// ---------------------------------------------------------------------------
__global__ __launch_bounds__(FPS_T, 2) void fps_kernel(
    const float* __restrict__ xyz, const float* __restrict__ gs,
    float* __restrict__ out_f, int* __restrict__ out_i,
    int* __restrict__ cidx, float* __restrict__ cx,
    float* __restrict__ cy, float* __restrict__ cz)
{
    int b = blockIdx.x;
    int t = threadIdx.x;
    __shared__ int sA[FPS_T], sB[FPS_T];
    __shared__ unsigned long long pkL[2][8];
    __shared__ int hist[NSAMP];
    __shared__ float cxL[LDSM], cyL[LDSM], czL[LDSM];
    __shared__ int cidxL[LDSM];

    const float* gsb = gs + (size_t)b * NPTS;
    const float* xb  = xyz + (size_t)b * NPTS * 3;

    // ---- phase 1: count valid in my contiguous chunk ----
    int base = t * MAXPP;
    unsigned long long vmask = 0ull;
    int cnt = 0;
#pragma unroll
    for (int j = 0; j < MAXPP; ++j) {
        int p = base + j;
        if (p < NPTS) {
            if (gsb[p] > 0.09f) { vmask |= (1ull << j); ++cnt; }
        }
    }
    sA[t] = cnt;
    __syncthreads();
    // Hillis-Steele inclusive scan (ping-pong)
    int* src = sA; int* dst = sB;
    for (int off = 1; off < FPS_T; off <<= 1) {
        int v = src[t];
        if (t >= off) v += src[t - off];
        dst[t] = v;
        __syncthreads();
        int* tmp = src; src = dst; dst = tmp;
    }
    int M = src[FPS_T - 1];
    int excl = src[t] - cnt;
    bool useLds = (M <= LDSM);

    // ---- ordered compacted write (preserves index order => argmax ties OK) ----
    {
        int pos = excl;
#pragma unroll
        for (int j = 0; j < MAXPP; ++j) {
            if (vmask & (1ull << j)) {
                int p = base + j;
                if (useLds) {
                    cidxL[pos] = p;
                    cxL[pos] = xb[p * 3 + 0];
                    cyL[pos] = xb[p * 3 + 1];
                    czL[pos] = xb[p * 3 + 2];
                } else {
                    int gp = b * NPTS + pos;
                    cidx[gp] = p;
                    cx[gp] = xb[p * 3 + 0];
                    cy[gp] = xb[p * 3 + 1];
                    cz[gp] = xb[p * 3 + 2];
                }
                ++pos;
            }
        }
    }
    __syncthreads();

    if (M > 0) {
        const float* cxg = cx + b * NPTS;
        const float* cyg = cy + b * NPTS;
        const float* czg = cz + b * NPTS;

        if (useLds) {
            fps_core2<8, true>(t, M, (M + FPS_T - 1) / FPS_T, cxg, cyg, czg,
                               cxL, cyL, czL, hist, pkL);
        } else {
            int cnt2 = (M + FPS_T - 1) / FPS_T;
            if (cnt2 <= 16)      fps_core2<16, false>(t, M, cnt2, cxg, cyg, czg, cxL, cyL, czL, hist, pkL);
            else if (cnt2 <= 24) fps_core2<24, false>(t, M, cnt2, cxg, cyg, czg, cxL, cyL, czL, hist, pkL);
            else                 fps_core2<40, false>(t, M, cnt2, cxg, cyg, czg, cxL, cyL, czL, hist, pkL);
        }

        __syncthreads();
        for (int s = t; s < NSAMP; s += FPS_T) {
            int hp = hist[s];
            int oi = useLds ? cidxL[hp] : cidx[b * NPTS + hp];
            out_f[b * NSAMP + s] = (float)oi;
            out_i[b * NSAMP + s] = oi;
        }
    } else {
        for (int s = t; s < NSAMP; s += FPS_T) {
            out_f[b * NSAMP + s] = 0.f;
            out_i[b * NSAMP + s] = 0;
        }
    }
}

// ---------------------------------------------------------------------------
// gathers
// ---------------------------------------------------------------------------
__global__ void gather_xyz_kernel(const float* __restrict__ xyz,
                                  const int* __restrict__ inds,
                                  float* __restrict__ dout)
{
    int i = blockIdx.x * 256 + threadIdx.x;
    if (i >= NB * NSAMP) return;
    int b = i >> 10;
    int ind = inds[i];
    const float* p = xyz + ((size_t)b * NPTS + ind) * 3;
    dout[O_XYZ + (size_t)i * 3 + 0] = p[0];
    dout[O_XYZ + (size_t)i * 3 + 1] = p[1];
    dout[O_XYZ + (size_t)i * 3 + 2] = p[2];
    dout[O_FP2 + i] = dout[O_GS + (size_t)b * NPTS + ind];
}

__global__ void gather_feat_kernel(const float* __restrict__ feat,
                                   const int* __restrict__ inds,
                                   float* __restrict__ dout)
{
    int c = blockIdx.x, b = blockIdx.y, s = threadIdx.x;   // 1024 threads
    int ind = inds[b * NSAMP + s];
    dout[O_FEAT + ((size_t)b * NC + c) * NSAMP + s] =
        feat[((size_t)b * NC + c) * NPTS + ind];
}

// ---------------------------------------------------------------------------
// fp32 tiled GEMM with T14 register prefetch: kt+1 tile loads issued before
// kt compute; LDS writes after the post-compute barrier. Same barrier count.
// EPI 0/1: +bias, BN, ReLU -> Cdst[b][c][n].
// EPI 2:   +bias -> d_out transposed [B,NS,V] via LDS-staged coalesced store.
// ---------------------------------------------------------------------------
template<int EPI>
__global__ __launch_bounds__(256) void gemm_epi_kernel(
    const float* __restrict__ A, const float* __restrict__ Bsrc,
    int M, int K, size_t bstride,
    const float* __restrict__ bias, const float* __restrict__ gg,
    const float* __restrict__ bb, const float* __restrict__ mm,
    const float* __restrict__ vv,
    float* __restrict__ Cdst, size_t cstride)
{
    __shared__ float As[16][68];
    __shared__ float Bs[16][68];
    __shared__ float Cs[64][65];   // EPI2 transpose staging (unused otherwise)
    int tid = threadIdx.x;
    int n0 = blockIdx.x * 64;
    int m0 = blockIdx.y * 64;
    int b  = blockIdx.z;
    const float* Bb = Bsrc + (size_t)b * bstride;
    int tx = tid & 15, ty = tid >> 4;
    int bk = tid >> 6, bn = tid & 63;      // B-tile staging coords
    float acc[4][4] = {};
    int nk = (K + 15) >> 4;

    float a_reg[4], b_reg[4];
    // prologue: tile kt=0 -> regs -> LDS
#pragma unroll
    for (int p = 0; p < 4; ++p) {
        int m_l = ty + p * 16;
        int gm = m0 + m_l;
        a_reg[p] = (gm < M && tx < K) ? A[(size_t)gm * K + tx] : 0.f;
    }
#pragma unroll
    for (int p = 0; p < 4; ++p) {
        int k_l = bk + p * 4;
        b_reg[p] = (k_l < K) ? Bb[(size_t)k_l * NSAMP + n0 + bn] : 0.f;
    }
#pragma unroll
    for (int p = 0; p < 4; ++p) As[tx][ty + p * 16] = a_reg[p];
#pragma unroll
    for (int p = 0; p < 4; ++p) Bs[bk + p * 4][bn] = b_reg[p];
    __syncthreads();

    for (int kt = 0; kt < nk; ++kt) {
        // T14: prefetch kt+1 into registers before compute
        if (kt + 1 < nk) {
            int k0 = (kt + 1) * 16;
#pragma unroll
            for (int p = 0; p < 4; ++p) {
                int m_l = ty + p * 16;
                int gm = m0 + m_l, gk = k0 + tx;
                a_reg[p] = (gm < M && gk < K) ? A[(size_t)gm * K + gk] : 0.f;
            }
#pragma unroll
            for (int p = 0; p < 4; ++p) {
                int gk = k0 + bk + p * 4;
                b_reg[p] = (gk < K) ? Bb[(size_t)gk * NSAMP + n0 + bn] : 0.f;
            }
        }

#pragma unroll
        for (int kk = 0; kk < 16; ++kk) {
            float a0 = As[kk][ty * 4 + 0], a1 = As[kk][ty * 4 + 1];
            float a2 = As[kk][ty * 4 + 2], a3 = As[kk][ty * 4 + 3];
            float c0 = Bs[kk][tx * 4 + 0], c1 = Bs[kk][tx * 4 + 1];
            float c2 = Bs[kk][tx * 4 + 2], c3 = Bs[kk][tx * 4 + 3];
            acc[0][0] += a0 * c0; acc[0][1] += a0 * c1; acc[0][2] += a0 * c2; acc[0][3] += a0 * c3;
            acc[1][0] += a1 * c0; acc[1][1] += a1 * c1; acc[1][2] += a1 * c2; acc[1][3] += a1 * c3;
            acc[2][0] += a2 * c0; acc[2][1] += a2 * c1; acc[2][2] += a2 * c2; acc[2][3] += a2 * c3;
            acc[3][0] += a3 * c0; acc[3][1] += a3 * c1; acc[3][2] += a3 * c2; acc[3][3] += a3 * c3;
        }
        __syncthreads();
        if (kt + 1 < nk) {
#pragma unroll
            for (int p = 0; p < 4; ++p) As[tx][ty + p * 16] = a_reg[p];
#pragma unroll
            for (int p = 0; p < 4; ++p) Bs[bk + p * 4][bn] = b_reg[p];
            __syncthreads();
        }
    }

#pragma unroll
    for (int i = 0; i < 4; ++i) {
        int c = m0 + ty * 4 + i;
        if (c >= M) continue;
        float bi = bias[c];
        float scl = 0.f, sh = 0.f, mc = 0.f;
        if constexpr (EPI < 2) {
            scl = gg[c] / sqrtf(vv[c] + 1e-5f);
            sh = bb[c];
            mc = mm[c];
        }
#pragma unroll
        for (int j = 0; j < 4; ++j) {
            int n = n0 + tx * 4 + j;
            float v = acc[i][j] + bi;
            if constexpr (EPI < 2) {
                v = (v - mc) * scl + sh;
                v = fmaxf(v, 0.f);
                Cdst[(size_t)b * cstride + (size_t)c * NSAMP + n] = v;
            } else {
                Cs[ty * 4 + i][tx * 4 + j] = v;   // stage for coalesced store
            }
        }
    }
    if constexpr (EPI == 2) {
        __syncthreads();
        for (int idx = tid; idx < 64 * 64; idx += 256) {
            int n_l = idx >> 6, c_l = idx & 63;
            int c = m0 + c_l;
            if (c < M)
                Cdst[((size_t)b * NSAMP + n0 + n_l) * NV + c] = Cs[c_l][n_l];
        }
    }
}

// ---------------------------------------------------------------------------
// final: per-(b,s) argmax over 300 views, fibonacci-sphere view (f64 like numpy),
// rotation matrix (angle = 0  =>  R = [axis_x | axis_y | axis_z])
// ---------------------------------------------------------------------------
__global__ void view_kernel(float* __restrict__ dout)
{
    int i = blockIdx.x * 256 + threadIdx.x;
    if (i >= NB * NSAMP) return;
    const float* vs = dout + O_VS + (size_t)i * NV;
    float best = vs[0]; int bi = 0;
    for (int v = 1; v < NV; ++v) {
        float x = vs[v];
        if (x > best) { best = x; bi = v; }
    }
    dout[O_TVS + i] = best;
    dout[O_TVI + i] = (float)bi;

    const double PHI = (sqrt(5.0) - 1.0) / 2.0;
    double z = (2.0 * (double)bi + 1.0) / 300.0 - 1.0;
    double rr = sqrt(fmax(1.0 - z * z, 0.0));
    double ang = (2.0 * 3.14159265358979323846 * (double)bi) * PHI;
    float vx = (float)(rr * cos(ang));
    float vy = (float)(rr * sin(ang));
    float vz = (float)z;
    dout[O_VPX + (size_t)i * 3 + 0] = vx;
    dout[O_VPX + (size_t)i * 3 + 1] = vy;
    dout[O_VPX + (size_t)i * 3 + 2] = vz;

    float tx = -vx, ty = -vy, tz = -vz;
    float ayx = -ty, ayy = tx, ayz = 0.f;
    float ny = sqrtf(ayx * ayx + ayy * ayy + ayz * ayz);
    if (ny == 0.f) { ayx = 0.f; ayy = 1.f; ayz = 0.f; }
    float nx = sqrtf(tx * tx + ty * ty + tz * tz);
    float axx = tx / nx, axy = ty / nx, axz = tz / nx;
    float ny2 = sqrtf(ayx * ayx + ayy * ayy + ayz * ayz);
    ayx /= ny2; ayy /= ny2; ayz /= ny2;
    float azx = axy * ayz - axz * ayy;
    float azy = axz * ayx - axx * ayz;
    float azz = axx * ayy - axy * ayx;
    float* R = dout + O_ROT + (size_t)i * 9;
    R[0] = axx; R[1] = ayx; R[2] = azx;
    R[3] = axy; R[4] = ayy; R[5] = azy;
    R[6] = axz; R[7] = ayz; R[8] = azz;
}

// ---------------------------------------------------------------------------
extern "C" void kernel_launch(void* const* d_in, const int* in_sizes, int n_in,
                              void* d_out, int out_size, void* d_ws, size_t ws_size,
                              hipStream_t stream)
{
    const float* seed_xyz  = (const float*)d_in[0];
    const float* seed_feat = (const float*)d_in[1];
    const float* gh_w1 = (const float*)d_in[2];
    const float* gh_b1 = (const float*)d_in[3];
    const float* gh_g1 = (const float*)d_in[4];
    const float* gh_be1 = (const float*)d_in[5];
    const float* gh_m1 = (const float*)d_in[6];
    const float* gh_v1 = (const float*)d_in[7];
    const float* gh_w2 = (const float*)d_in[8];
    const float* gh_b2 = (const float*)d_in[9];
    const float* w1 = (const float*)d_in[10];
    const float* b1 = (const float*)d_in[11];
    const float* g1 = (const float*)d_in[12];
    const float* be1 = (const float*)d_in[13];
    const float* m1 = (const float*)d_in[14];
    const float* v1 = (const float*)d_in[15];
    const float* w2 = (const float*)d_in[16];
    const float* b2 = (const float*)d_in[17];
    const float* g2 = (const float*)d_in[18];
    const float* be2 = (const float*)d_in[19];
    const float* m2 = (const float*)d_in[20];
    const float* v2 = (const float*)d_in[21];
    const float* w3 = (const float*)d_in[22];
    const float* b3 = (const float*)d_in[23];

    float* out = (float*)d_out;

    // workspace layout (~10.4 MB)
    int*   ws_inds = (int*)d_ws;                     // B*NS
    int*   ws_cidx = ws_inds + NB * NSAMP;           // B*NPTS
    float* ws_cx = (float*)(ws_cidx + NB * NPTS);    // B*NPTS
    float* ws_cy = ws_cx + NB * NPTS;
    float* ws_cz = ws_cy + NB * NPTS;
    float* ws_g1 = ws_cz + NB * NPTS;                // B*256*1024
    float* ws_g2 = ws_g1 + (size_t)NB * NC * NSAMP;  // B*300*1024

    graspness_kernel<<<dim3(313, 1, NB), 512, 0, stream>>>(
        seed_feat, gh_w1, gh_b1, gh_g1, gh_be1, gh_m1, gh_v1, gh_w2, gh_b2,
        out + O_GS);

    fps_kernel<<<NB, FPS_T, 0, stream>>>(
        seed_xyz, out + O_GS, out + O_INDS, ws_inds,
        ws_cidx, ws_cx, ws_cy, ws_cz);

    gather_xyz_kernel<<<(NB * NSAMP + 255) / 256, 256, 0, stream>>>(
        seed_xyz, ws_inds, out);

    gather_feat_kernel<<<dim3(NC, NB), 1024, 0, stream>>>(
        seed_feat, ws_inds, out);

    gemm_epi_kernel<0><<<dim3(16, 4, NB), 256, 0, stream>>>(
        w1, out + O_FEAT, NC, NC, (size_t)NC * NSAMP,
        b1, g1, be1, m1, v1, ws_g1, (size_t)NC * NSAMP);

    gemm_epi_kernel<1><<<dim3(16, 5, NB), 256, 0, stream>>>(
        w2, ws_g1, NV, NC, (size_t)NC * NSAMP,
        b2, g2, be2, m2, v2, ws_g2, (size_t)NV * NSAMP);

    gemm_epi_kernel<2><<<dim3(16, 5, NB), 256, 0, stream>>>(
        w3, ws_g2, NV, NV, (size_t)NV * NSAMP,
        b3, nullptr, nullptr, nullptr, nullptr, out + O_VS, 0);

    view_kernel<<<(NB * NSAMP + 255) / 256, 256, 0, stream>>>(out);
}

// Round 12
// 1088.256 us; speedup vs baseline: 2.5322x; 1.1045x over previous
//
#include <hip/hip_runtime.h>
#include <math.h>

#define NB 4
#define NPTS 20000
#define NC 256
#define NV 300
#define NSAMP 1024

// d_out float offsets (outputs concatenated flat in reference return order)
#define O_GS    0         // graspness_score  [B,N]
#define O_INDS  80000     // graspable_inds   [B,NS] (as float)
#define O_XYZ   84096     // graspable_xyz    [B,NS,3]
#define O_FEAT  96384     // graspable_feats  [B,C,NS]
#define O_FP2   1144960   // fp2_graspness    [B,NS]
#define O_VS    1149056   // view_score       [B,NS,V]
#define O_TVI   2377856   // top_view_inds    [B,NS] (as float)
#define O_TVS   2381952   // top_view_scores  [B,NS]
#define O_VPX   2386048   // vp_xyz           [B,NS,3]
#define O_ROT   2398336   // vp_rot           [B,NS,3,3]

#define FPS_T 512
#define MAXPP 40     // ceil(NPTS / FPS_T)
#define LDSM  4096   // max compacted points kept in LDS

// component select with compile-time c (folds after full unroll)
__device__ __forceinline__ float f4c(const float4& v, int c)
{
    return c == 0 ? v.x : c == 1 ? v.y : c == 2 ? v.z : v.w;
}

// ---------------------------------------------------------------------------
// Kernel A v5: fused graspable head. W1 read DIRECTLY to registers (each
// thread only consumes its own 2 o-rows per ob; L2-resident, lane-broadcast)
// -> no As staging, and NO per-stage barriers (Fs read-only after load, Xs
// single-writer): exactly 2 barriers in the whole kernel; 8 waves free-run.
// Numerics bit-identical: per-(o,j) 4-partial chains keyed c=k%4, ascending
// k (q outer, c inner: k = 16*kt + 4*q + c), combine (c0+c1)+(c2+c3)+b1[o],
// same BN/ReLU, sequential w2-dot over o=0..255.
// ---------------------------------------------------------------------------
__global__ __launch_bounds__(512, 2) void graspness_kernel(
    const float* __restrict__ feat, const float* __restrict__ w1,
    const float* __restrict__ b1, const float* __restrict__ g1,
    const float* __restrict__ be1, const float* __restrict__ m1,
    const float* __restrict__ v1, const float* __restrict__ w2,
    const float* __restrict__ b2, float* __restrict__ out)
{
    __shared__ float Fs[NC][64];     // 64 KB: full K x 64 points
    __shared__ float Xs[NC][65];     // 66.6 KB: relu(bn(conv)) tile (+1 pad)

    int b  = blockIdx.z;
    int n0 = blockIdx.x * 64;
    int tid = threadIdx.x;           // 0..511
    int tx = tid & 15;               // j quad: j = tx*4 + jj
    int ty = tid >> 4;               // 0..31: o pair: o = ob*64 + ty*2 + i
    int rem = NPTS - n0; if (rem > 64) rem = 64;

    // ---- load F tile [256 k][64 n] with 512 threads ----
    {
        int j  = tid & 63;
        int kb = tid >> 6;                       // 0..7
        const float* fb = feat + (size_t)b * NC * NPTS + n0;
        bool ok = (j < rem);
#pragma unroll
        for (int r = 0; r < 32; ++r) {
            int k = r * 8 + kb;
            Fs[k][j] = ok ? fb[(size_t)k * NPTS + j] : 0.f;
        }
    }
    __syncthreads();   // barrier 1 of 2

    float4 cur0[4], cur1[4], nxt0[4], nxt1[4];
    // prologue: stage 0 (ob=0, kt=0) W1 rows ty*2, ty*2+1, k=0..15
    {
        const float* p0 = w1 + (size_t)(ty * 2) * NC;
        const float* p1 = p0 + NC;
#pragma unroll
        for (int q = 0; q < 4; ++q) {
            cur0[q] = *reinterpret_cast<const float4*>(&p0[q * 4]);
            cur1[q] = *reinterpret_cast<const float4*>(&p1[q * 4]);
        }
    }

    float acc[2][4][4];   // [i o][j pt][c = k%4] -- statically indexed

#pragma unroll 1
    for (int s = 0; s < 64; ++s) {
        int ob = s >> 4, kt = s & 15;

        if (kt == 0) {
#pragma unroll
            for (int i = 0; i < 2; ++i)
#pragma unroll
                for (int j = 0; j < 4; ++j)
#pragma unroll
                    for (int c = 0; c < 4; ++c) acc[i][j][c] = 0.f;
        }

        // prefetch next stage's W1 rows into registers (T14, no LDS)
        if (s + 1 < 64) {
            int ob2 = (s + 1) >> 4, kt2 = (s + 1) & 15;
            const float* p0 = w1 + (size_t)(ob2 * 64 + ty * 2) * NC + kt2 * 16;
            const float* p1 = p0 + NC;
#pragma unroll
            for (int q = 0; q < 4; ++q) {
                nxt0[q] = *reinterpret_cast<const float4*>(&p0[q * 4]);
                nxt1[q] = *reinterpret_cast<const float4*>(&p1[q * 4]);
            }
        }

        // compute: k = kt*16 + q*4 + c ascending (q outer, c inner)
#pragma unroll
        for (int q = 0; q < 4; ++q) {
#pragma unroll
            for (int c = 0; c < 4; ++c) {
                float ax = f4c(cur0[q], c);
                float ay = f4c(cur1[q], c);
                float4 f = *reinterpret_cast<const float4*>(
                    &Fs[kt * 16 + q * 4 + c][tx * 4]);
                acc[0][0][c] += ax * f.x; acc[0][1][c] += ax * f.y;
                acc[0][2][c] += ax * f.z; acc[0][3][c] += ax * f.w;
                acc[1][0][c] += ay * f.x; acc[1][1][c] += ay * f.y;
                acc[1][2][c] += ay * f.z; acc[1][3][c] += ay * f.w;
            }
        }

        if (kt == 15) {
#pragma unroll
            for (int i = 0; i < 2; ++i) {
                int o = ob * 64 + ty * 2 + i;
                float bo = b1[o];
                float sc = g1[o] / sqrtf(v1[o] + 1e-5f);
                float mo = m1[o], beo = be1[o];
#pragma unroll
                for (int j = 0; j < 4; ++j) {
                    float y = (acc[i][j][0] + acc[i][j][1]) +
                              (acc[i][j][2] + acc[i][j][3]) + bo;
                    float r = (y - mo) * sc + beo;
                    r = fmaxf(r, 0.f);
                    Xs[o][tx * 4 + j] = r;
                }
            }
        }

#pragma unroll
        for (int q = 0; q < 4; ++q) { cur0[q] = nxt0[q]; cur1[q] = nxt1[q]; }
    }

    __syncthreads();   // barrier 2 of 2

    // ---- w2 dot: sequential over o = 0..255, same order as before ----
    if (tid < 64 && tid < rem) {
        float gs = 0.f;
#pragma unroll 8
        for (int o = 0; o < NC; ++o) {
            gs += w2[o] * Xs[o][tid];
        }
        out[(size_t)b * NPTS + n0 + tid] = gs + b2[0];
    }
}

// ---------------------------------------------------------------------------
// cross-lane helper
// ---------------------------------------------------------------------------
template<int CTRL>
__device__ __forceinline__ unsigned long long dpp_u64(unsigned long long x)
{
    int lo = __builtin_amdgcn_update_dpp(0, (int)(unsigned)(x & 0xffffffffull),
                                         CTRL, 0xF, 0xF, false);
    int hi = __builtin_amdgcn_update_dpp(0, (int)(unsigned)(x >> 32),
                                         CTRL, 0xF, 0xF, false);
    return ((unsigned long long)(unsigned)hi << 32) | (unsigned)lo;
}

// ---------------------------------------------------------------------------
// FPS core v5 (frozen; measured 738 us): 8-wave structure, all-DPP wave
// reduce to lane 63, 8-entry LDS tree, parity double-buffer.
// ---------------------------------------------------------------------------
template<int TIER, bool USE_LDS>
__device__ __forceinline__ void fps_core2(
    int t, int M, int cnt2,
    const float* __restrict__ cxg, const float* __restrict__ cyg,
    const float* __restrict__ czg,
    const float* __restrict__ cxL, const float* __restrict__ cyL,
    const float* __restrict__ czL,
    int* __restrict__ hist, unsigned long long (*pkL)[8])
{
    int mybase = t * cnt2;
    int mycount = M - mybase;
    if (mycount > cnt2) mycount = cnt2;
    if (mycount < 0) mycount = 0;

    float rx[TIER], ry[TIER], rz[TIER], dd[TIER];
#pragma unroll
    for (int j = 0; j < TIER; ++j) {
        if (j < mycount) {
            rx[j] = USE_LDS ? cxL[mybase + j] : cxg[mybase + j];
            ry[j] = USE_LDS ? cyL[mybase + j] : cyg[mybase + j];
            rz[j] = USE_LDS ? czL[mybase + j] : czg[mybase + j];
            dd[j] = 1e10f;
        }
    }

    float wx = USE_LDS ? cxL[0] : cxg[0];
    float wy = USE_LDS ? cyL[0] : cyg[0];
    float wz = USE_LDS ? czL[0] : czg[0];
    int winner = 0;
    int w = t >> 6;

    for (int it = 0; it < NSAMP; ++it) {
        if (t == 0) hist[it] = winner;

        float bv = -2.f; int bc = 0x7fffffff;
#pragma unroll
        for (int j = 0; j < TIER; ++j) {
            if (j < mycount) {
                float dx = __fsub_rn(rx[j], wx);
                float dy = __fsub_rn(ry[j], wy);
                float dz = __fsub_rn(rz[j], wz);
                float d  = __fadd_rn(__fadd_rn(__fmul_rn(dx, dx), __fmul_rn(dy, dy)),
                                     __fmul_rn(dz, dz));
                float nd = fminf(dd[j], d);
                dd[j] = nd;
                if (nd > bv) { bv = nd; bc = mybase + j; }
            }
        }

        // packed key: value bits (>=0, unsigned-monotonic) | ~pos (min pos on ties)
        unsigned long long pk = (bc == 0x7fffffff)
            ? 0ull
            : (((unsigned long long)__float_as_uint(bv) << 32) | (unsigned)(~bc));

        // all-DPP wave max-reduce; valid in lane 63 (VALU-only, no LDS pipe)
        { unsigned long long o = dpp_u64<0xB1>(pk);  if (o > pk) pk = o; }  // quad xor1
        { unsigned long long o = dpp_u64<0x4E>(pk);  if (o > pk) pk = o; }  // quad xor2
        { unsigned long long o = dpp_u64<0x124>(pk); if (o > pk) pk = o; }  // row_ror:4
        { unsigned long long o = dpp_u64<0x128>(pk); if (o > pk) pk = o; }  // row_ror:8
        { unsigned long long o = dpp_u64<0x142>(pk); if (o > pk) pk = o; }  // row_bcast15
        { unsigned long long o = dpp_u64<0x143>(pk); if (o > pk) pk = o; }  // row_bcast31

        int par = it & 1;   // parity double-buffer -> single barrier per iter
        if ((t & 63) == 63) pkL[par][w] = pk;
        __syncthreads();

        // 8-entry tree (all threads, broadcast LDS reads)
        unsigned long long a0 = pkL[par][0], a1 = pkL[par][1];
        unsigned long long a2 = pkL[par][2], a3 = pkL[par][3];
        unsigned long long a4 = pkL[par][4], a5 = pkL[par][5];
        unsigned long long a6 = pkL[par][6], a7 = pkL[par][7];
        if (a1 > a0) a0 = a1;
        if (a3 > a2) a2 = a3;
        if (a5 > a4) a4 = a5;
        if (a7 > a6) a6 = a7;
        if (a2 > a0) a0 = a2;
        if (a6 > a4) a4 = a6;
        if (a4 > a0) a0 = a4;

        int pos = (int)(~(unsigned)(a0 & 0xffffffffull));
        winner = pos;
        wx = USE_LDS ? cxL[pos] : cxg[pos];
        wy = USE_LDS ? cyL[pos] : cyg[pos];
        wz = USE_LDS ? czL[pos] : czg[pos];
    }
}

// ---------------------------------------------------------------------------
// Kernel B: per-batch masked FPS (one workgroup per batch). Unchanged.
// ---------------------------------------------------------------------------
__global__ __launch_bounds__(FPS_T, 2) void fps_kernel(
    const float* __restrict__ xyz, const float* __restrict__ gs,
    float* __restrict__ out_f, int* __restrict__ out_i,
    int* __restrict__ cidx, float* __restrict__ cx,
    float* __restrict__ cy, float* __restrict__ cz)
{
    int b = blockIdx.x;
    int t = threadIdx.x;
    __shared__ int sA[FPS_T], sB[FPS_T];
    __shared__ unsigned long long pkL[2][8];
    __shared__ int hist[NSAMP];
    __shared__ float cxL[LDSM], cyL[LDSM], czL[LDSM];
    __shared__ int cidxL[LDSM];

    const float* gsb = gs + (size_t)b * NPTS;
    const float* xb  = xyz + (size_t)b * NPTS * 3;

    // ---- phase 1: count valid in my contiguous chunk ----
    int base = t * MAXPP;
    unsigned long long vmask = 0ull;
    int cnt = 0;
#pragma unroll
    for (int j = 0; j < MAXPP; ++j) {
        int p = base + j;
        if (p < NPTS) {
            if (gsb[p] > 0.09f) { vmask |= (1ull << j); ++cnt; }
        }
    }
    sA[t] = cnt;
    __syncthreads();
    // Hillis-Steele inclusive scan (ping-pong)
    int* src = sA; int* dst = sB;
    for (int off = 1; off < FPS_T; off <<= 1) {
        int v = src[t];
        if (t >= off) v += src[t - off];
        dst[t] = v;
        __syncthreads();
        int* tmp = src; src = dst; dst = tmp;
    }
    int M = src[FPS_T - 1];
    int excl = src[t] - cnt;
    bool useLds = (M <= LDSM);

    // ---- ordered compacted write (preserves index order => argmax ties OK) ----
    {
        int pos = excl;
#pragma unroll
        for (int j = 0; j < MAXPP; ++j) {
            if (vmask & (1ull << j)) {
                int p = base + j;
                if (useLds) {
                    cidxL[pos] = p;
                    cxL[pos] = xb[p * 3 + 0];
                    cyL[pos] = xb[p * 3 + 1];
                    czL[pos] = xb[p * 3 + 2];
                } else {
                    int gp = b * NPTS + pos;
                    cidx[gp] = p;
                    cx[gp] = xb[p * 3 + 0];
                    cy[gp] = xb[p * 3 + 1];
                    cz[gp] = xb[p * 3 + 2];
                }
                ++pos;
            }
        }
    }
    __syncthreads();

    if (M > 0) {
        const float* cxg = cx + b * NPTS;
        const float* cyg = cy + b * NPTS;
        const float* czg = cz + b * NPTS;

        if (useLds) {
            fps_core2<8, true>(t, M, (M + FPS_T - 1) / FPS_T, cxg, cyg, czg,
                               cxL, cyL, czL, hist, pkL);
        } else {
            int cnt2 = (M + FPS_T - 1) / FPS_T;
            if (cnt2 <= 16)      fps_core2<16, false>(t, M, cnt2, cxg, cyg, czg, cxL, cyL, czL, hist, pkL);
            else if (cnt2 <= 24) fps_core2<24, false>(t, M, cnt2, cxg, cyg, czg, cxL, cyL, czL, hist, pkL);
            else                 fps_core2<40, false>(t, M, cnt2, cxg, cyg, czg, cxL, cyL, czL, hist, pkL);
        }

        __syncthreads();
        for (int s = t; s < NSAMP; s += FPS_T) {
            int hp = hist[s];
            int oi = useLds ? cidxL[hp] : cidx[b * NPTS + hp];
            out_f[b * NSAMP + s] = (float)oi;
            out_i[b * NSAMP + s] = oi;
        }
    } else {
        for (int s = t; s < NSAMP; s += FPS_T) {
            out_f[b * NSAMP + s] = 0.f;
            out_i[b * NSAMP + s] = 0;
        }
    }
}

// ---------------------------------------------------------------------------
// gathers
// ---------------------------------------------------------------------------
__global__ void gather_xyz_kernel(const float* __restrict__ xyz,
                                  const int* __restrict__ inds,
                                  float* __restrict__ dout)
{
    int i = blockIdx.x * 256 + threadIdx.x;
    if (i >= NB * NSAMP) return;
    int b = i >> 10;
    int ind = inds[i];
    const float* p = xyz + ((size_t)b * NPTS + ind) * 3;
    dout[O_XYZ + (size_t)i * 3 + 0] = p[0];
    dout[O_XYZ + (size_t)i * 3 + 1] = p[1];
    dout[O_XYZ + (size_t)i * 3 + 2] = p[2];
    dout[O_FP2 + i] = dout[O_GS + (size_t)b * NPTS + ind];
}

__global__ void gather_feat_kernel(const float* __restrict__ feat,
                                   const int* __restrict__ inds,
                                   float* __restrict__ dout)
{
    int c = blockIdx.x, b = blockIdx.y, s = threadIdx.x;   // 1024 threads
    int ind = inds[b * NSAMP + s];
    dout[O_FEAT + ((size_t)b * NC + c) * NSAMP + s] =
        feat[((size_t)b * NC + c) * NPTS + ind];
}

// ---------------------------------------------------------------------------
// fp32 tiled GEMM with T14 register prefetch: kt+1 tile loads issued before
// kt compute; LDS writes after the post-compute barrier. Same barrier count.
// EPI 0/1: +bias, BN, ReLU -> Cdst[b][c][n].
// EPI 2:   +bias -> d_out transposed [B,NS,V] via LDS-staged coalesced store.
// ---------------------------------------------------------------------------
template<int EPI>
__global__ __launch_bounds__(256) void gemm_epi_kernel(
    const float* __restrict__ A, const float* __restrict__ Bsrc,
    int M, int K, size_t bstride,
    const float* __restrict__ bias, const float* __restrict__ gg,
    const float* __restrict__ bb, const float* __restrict__ mm,
    const float* __restrict__ vv,
    float* __restrict__ Cdst, size_t cstride)
{
    __shared__ float As[16][68];
    __shared__ float Bs[16][68];
    __shared__ float Cs[64][65];   // EPI2 transpose staging (unused otherwise)
    int tid = threadIdx.x;
    int n0 = blockIdx.x * 64;
    int m0 = blockIdx.y * 64;
    int b  = blockIdx.z;
    const float* Bb = Bsrc + (size_t)b * bstride;
    int tx = tid & 15, ty = tid >> 4;
    int bk = tid >> 6, bn = tid & 63;      // B-tile staging coords
    float acc[4][4] = {};
    int nk = (K + 15) >> 4;

    float a_reg[4], b_reg[4];
    // prologue: tile kt=0 -> regs -> LDS
#pragma unroll
    for (int p = 0; p < 4; ++p) {
        int m_l = ty + p * 16;
        int gm = m0 + m_l;
        a_reg[p] = (gm < M && tx < K) ? A[(size_t)gm * K + tx] : 0.f;
    }
#pragma unroll
    for (int p = 0; p < 4; ++p) {
        int k_l = bk + p * 4;
        b_reg[p] = (k_l < K) ? Bb[(size_t)k_l * NSAMP + n0 + bn] : 0.f;
    }
#pragma unroll
    for (int p = 0; p < 4; ++p) As[tx][ty + p * 16] = a_reg[p];
#pragma unroll
    for (int p = 0; p < 4; ++p) Bs[bk + p * 4][bn] = b_reg[p];
    __syncthreads();

    for (int kt = 0; kt < nk; ++kt) {
        // T14: prefetch kt+1 into registers before compute
        if (kt + 1 < nk) {
            int k0 = (kt + 1) * 16;
#pragma unroll
            for (int p = 0; p < 4; ++p) {
                int m_l = ty + p * 16;
                int gm = m0 + m_l, gk = k0 + tx;
                a_reg[p] = (gm < M && gk < K) ? A[(size_t)gm * K + gk] : 0.f;
            }
#pragma unroll
            for (int p = 0; p < 4; ++p) {
                int gk = k0 + bk + p * 4;
                b_reg[p] = (gk < K) ? Bb[(size_t)gk * NSAMP + n0 + bn] : 0.f;
            }
        }

#pragma unroll
        for (int kk = 0; kk < 16; ++kk) {
            float a0 = As[kk][ty * 4 + 0], a1 = As[kk][ty * 4 + 1];
            float a2 = As[kk][ty * 4 + 2], a3 = As[kk][ty * 4 + 3];
            float c0 = Bs[kk][tx * 4 + 0], c1 = Bs[kk][tx * 4 + 1];
            float c2 = Bs[kk][tx * 4 + 2], c3 = Bs[kk][tx * 4 + 3];
            acc[0][0] += a0 * c0; acc[0][1] += a0 * c1; acc[0][2] += a0 * c2; acc[0][3] += a0 * c3;
            acc[1][0] += a1 * c0; acc[1][1] += a1 * c1; acc[1][2] += a1 * c2; acc[1][3] += a1 * c3;
            acc[2][0] += a2 * c0; acc[2][1] += a2 * c1; acc[2][2] += a2 * c2; acc[2][3] += a2 * c3;
            acc[3][0] += a3 * c0; acc[3][1] += a3 * c1; acc[3][2] += a3 * c2; acc[3][3] += a3 * c3;
        }
        __syncthreads();
        if (kt + 1 < nk) {
#pragma unroll
            for (int p = 0; p < 4; ++p) As[tx][ty + p * 16] = a_reg[p];
#pragma unroll
            for (int p = 0; p < 4; ++p) Bs[bk + p * 4][bn] = b_reg[p];
            __syncthreads();
        }
    }

#pragma unroll
    for (int i = 0; i < 4; ++i) {
        int c = m0 + ty * 4 + i;
        if (c >= M) continue;
        float bi = bias[c];
        float scl = 0.f, sh = 0.f, mc = 0.f;
        if constexpr (EPI < 2) {
            scl = gg[c] / sqrtf(vv[c] + 1e-5f);
            sh = bb[c];
            mc = mm[c];
        }
#pragma unroll
        for (int j = 0; j < 4; ++j) {
            int n = n0 + tx * 4 + j;
            float v = acc[i][j] + bi;
            if constexpr (EPI < 2) {
                v = (v - mc) * scl + sh;
                v = fmaxf(v, 0.f);
                Cdst[(size_t)b * cstride + (size_t)c * NSAMP + n] = v;
            } else {
                Cs[ty * 4 + i][tx * 4 + j] = v;   // stage for coalesced store
            }
        }
    }
    if constexpr (EPI == 2) {
        __syncthreads();
        for (int idx = tid; idx < 64 * 64; idx += 256) {
            int n_l = idx >> 6, c_l = idx & 63;
            int c = m0 + c_l;
            if (c < M)
                Cdst[((size_t)b * NSAMP + n0 + n_l) * NV + c] = Cs[c_l][n_l];
        }
    }
}

// ---------------------------------------------------------------------------
// final: per-(b,s) argmax over 300 views, fibonacci-sphere view (f64 like numpy),
// rotation matrix (angle = 0  =>  R = [axis_x | axis_y | axis_z])
// ---------------------------------------------------------------------------
__global__ void view_kernel(float* __restrict__ dout)
{
    int i = blockIdx.x * 256 + threadIdx.x;
    if (i >= NB * NSAMP) return;
    const float* vs = dout + O_VS + (size_t)i * NV;
    float best = vs[0]; int bi = 0;
    for (int v = 1; v < NV; ++v) {
        float x = vs[v];
        if (x > best) { best = x; bi = v; }
    }
    dout[O_TVS + i] = best;
    dout[O_TVI + i] = (float)bi;

    const double PHI = (sqrt(5.0) - 1.0) / 2.0;
    double z = (2.0 * (double)bi + 1.0) / 300.0 - 1.0;
    double rr = sqrt(fmax(1.0 - z * z, 0.0));
    double ang = (2.0 * 3.14159265358979323846 * (double)bi) * PHI;
    float vx = (float)(rr * cos(ang));
    float vy = (float)(rr * sin(ang));
    float vz = (float)z;
    dout[O_VPX + (size_t)i * 3 + 0] = vx;
    dout[O_VPX + (size_t)i * 3 + 1] = vy;
    dout[O_VPX + (size_t)i * 3 + 2] = vz;

    float tx = -vx, ty = -vy, tz = -vz;
    float ayx = -ty, ayy = tx, ayz = 0.f;
    float ny = sqrtf(ayx * ayx + ayy * ayy + ayz * ayz);
    if (ny == 0.f) { ayx = 0.f; ayy = 1.f; ayz = 0.f; }
    float nx = sqrtf(tx * tx + ty * ty + tz * tz);
    float axx = tx / nx, axy = ty / nx, axz = tz / nx;
    float ny2 = sqrtf(ayx * ayx + ayy * ayy + ayz * ayz);
    ayx /= ny2; ayy /= ny2; ayz /= ny2;
    float azx = axy * ayz - axz * ayy;
    float azy = axz * ayx - axx * ayz;
    float azz = axx * ayy - axy * ayx;
    float* R = dout + O_ROT + (size_t)i * 9;
    R[0] = axx; R[1] = ayx; R[2] = azx;
    R[3] = axy; R[4] = ayy; R[5] = azy;
    R[6] = axz; R[7] = ayz; R[8] = azz;
}

// ---------------------------------------------------------------------------
extern "C" void kernel_launch(void* const* d_in, const int* in_sizes, int n_in,
                              void* d_out, int out_size, void* d_ws, size_t ws_size,
                              hipStream_t stream)
{
    const float* seed_xyz  = (const float*)d_in[0];
    const float* seed_feat = (const float*)d_in[1];
    const float* gh_w1 = (const float*)d_in[2];
    const float* gh_b1 = (const float*)d_in[3];
    const float* gh_g1 = (const float*)d_in[4];
    const float* gh_be1 = (const float*)d_in[5];
    const float* gh_m1 = (const float*)d_in[6];
    const float* gh_v1 = (const float*)d_in[7];
    const float* gh_w2 = (const float*)d_in[8];
    const float* gh_b2 = (const float*)d_in[9];
    const float* w1 = (const float*)d_in[10];
    const float* b1 = (const float*)d_in[11];
    const float* g1 = (const float*)d_in[12];
    const float* be1 = (const float*)d_in[13];
    const float* m1 = (const float*)d_in[14];
    const float* v1 = (const float*)d_in[15];
    const float* w2 = (const float*)d_in[16];
    const float* b2 = (const float*)d_in[17];
    const float* g2 = (const float*)d_in[18];
    const float* be2 = (const float*)d_in[19];
    const float* m2 = (const float*)d_in[20];
    const float* v2 = (const float*)d_in[21];
    const float* w3 = (const float*)d_in[22];
    const float* b3 = (const float*)d_in[23];

    float* out = (float*)d_out;

    // workspace layout (~10.4 MB)
    int*   ws_inds = (int*)d_ws;                     // B*NS
    int*   ws_cidx = ws_inds + NB * NSAMP;           // B*NPTS
    float* ws_cx = (float*)(ws_cidx + NB * NPTS);    // B*NPTS
    float* ws_cy = ws_cx + NB * NPTS;
    float* ws_cz = ws_cy + NB * NPTS;
    float* ws_g1 = ws_cz + NB * NPTS;                // B*256*1024
    float* ws_g2 = ws_g1 + (size_t)NB * NC * NSAMP;  // B*300*1024

    graspness_kernel<<<dim3(313, 1, NB), 512, 0, stream>>>(
        seed_feat, gh_w1, gh_b1, gh_g1, gh_be1, gh_m1, gh_v1, gh_w2, gh_b2,
        out + O_GS);

    fps_kernel<<<NB, FPS_T, 0, stream>>>(
        seed_xyz, out + O_GS, out + O_INDS, ws_inds,
        ws_cidx, ws_cx, ws_cy, ws_cz);

    gather_xyz_kernel<<<(NB * NSAMP + 255) / 256, 256, 0, stream>>>(
        seed_xyz, ws_inds, out);

    gather_feat_kernel<<<dim3(NC, NB), 1024, 0, stream>>>(
        seed_feat, ws_inds, out);

    gemm_epi_kernel<0><<<dim3(16, 4, NB), 256, 0, stream>>>(
        w1, out + O_FEAT, NC, NC, (size_t)NC * NSAMP,
        b1, g1, be1, m1, v1, ws_g1, (size_t)NC * NSAMP);

    gemm_epi_kernel<1><<<dim3(16, 5, NB), 256, 0, stream>>>(
        w2, ws_g1, NV, NC, (size_t)NC * NSAMP,
        b2, g2, be2, m2, v2, ws_g2, (size_t)NV * NSAMP);

    gemm_epi_kernel<2><<<dim3(16, 5, NB), 256, 0, stream>>>(
        w3, ws_g2, NV, NV, (size_t)NV * NSAMP,
        b3, nullptr, nullptr, nullptr, nullptr, out + O_VS, 0);

    view_kernel<<<(NB * NSAMP + 255) / 256, 256, 0, stream>>>(out);
}